// Round 8
// baseline (1120.065 us; speedup 1.0000x reference)
//
#include <hip/hip_runtime.h>
#include <stdint.h>

// LSTM_49357764165950 — MI355X (gfx950), round 8
// = R7-passing kernel byte-for-byte EXCEPT two isolated changes:
//  (A) SCOPE EXPERIMENT: fast-path exchange uses system-scope cache bits `sc0 sc1`
//      (store: write-through past any stale-able cache; load: bypass L1/L2, read the
//      coherence point). Theory: R4/R7's ~4us/step is stale-line serving under
//      sc0-only (sub-agent scope), not a fabric floor. Protocol/tags unchanged.
//  (B) wm0/wm1/bem tables padded +4 floats per 16 (index f -> f + (f>>4)*4): the 12
//      xtile table reads/step hit banks {0,16} only (8-way) = the real source of the
//      2.9e7 SQ_LDS_BANK_CONFLICT (identical across R4/R7 layout changes).
//
// Slot-reuse safety (2 slots, R4 chain): a block overwrites slot s with tag t+2 only
// after its gather of t+1 succeeded => all partners published t+1 => all partners
// passed their end-of-iter-(t-1) barrier => their slot-s reads (tag t) are complete.

typedef float  f32x4  __attribute__((ext_vector_type(4)));
typedef float  f32x2  __attribute__((ext_vector_type(2)));
typedef short  bf16x8 __attribute__((ext_vector_type(8)));
typedef unsigned int u32x4 __attribute__((ext_vector_type(4)));

#define SMEM_SZ 86016      // force 1 block/CU (co-residency for spin protocol)
#define T_STEPS 255
#define ROWB    80         // bytes per 32-col bf16 row (64B data + 16B pad)
#define FRAGB   2608       // 32*80 + 48B pad
#define XT(b)   ((b)*4*FRAGB)               // x frags kf 0..3   (0, 10432)
#define HT(b)   (8*FRAGB + (b)*8*FRAGB)     // h frags 0..7      (20864, 41728; end 62592)
#define WM_OFF  62592                       // wm0p[160] wm1p[160] bemp[160] f32 (padded)
#define H1_OFF  64512
#define C1_OFF  65536

#define AG_ST(p, v) __hip_atomic_store((p), (v), __ATOMIC_RELAXED, __HIP_MEMORY_SCOPE_AGENT)
#define AG_LD(p)    __hip_atomic_load((p),        __ATOMIC_RELAXED, __HIP_MEMORY_SCOPE_AGENT)

__device__ __forceinline__ unsigned short f2bf(float f){
  union { float f; unsigned int u; } v; v.f = f;
  unsigned int u = v.u;
  return (unsigned short)((u + 0x7fffu + ((u >> 16) & 1u)) >> 16);   // RTNE
}
__device__ __forceinline__ float sigf(float x){
  float e = __builtin_amdgcn_exp2f(-1.4426950408889634f * x);
  return __builtin_amdgcn_rcpf(1.0f + e);
}
__device__ __forceinline__ float tanh_(float x){
  float e = __builtin_amdgcn_exp2f(-2.8853900817779268f * x);
  return (1.0f - e) * __builtin_amdgcn_rcpf(1.0f + e);
}

__global__ void zero_ws(unsigned int* flags, unsigned int* outw){
  const unsigned idx = blockIdx.x*512u + threadIdx.x;
  if (idx < 16384u)        AG_ST(flags + idx, 0u);
  else if (idx < 540672u)  AG_ST(outw + (idx - 16384u), 0u);
}

__global__ void __launch_bounds__(256, 1)
lstm_k(const float* __restrict__ obs,
       const float* __restrict__ Wemb, const float* __restrict__ Bemb,
       const float* __restrict__ Wih,  const float* __restrict__ Whh,
       const float* __restrict__ bih,  const float* __restrict__ bhh,
       float* out, unsigned int* flags, unsigned int* hbuf)   // hbuf aliases out
{
  __shared__ __align__(16) char smem[SMEM_SZ];
  const int tid = threadIdx.x;
  const int l   = tid & 63;
  const int w   = tid >> 6;
  const int m   = w & 1;
  const int hf  = w >> 1;
  const int lc  = l & 15;
  const int lg  = l >> 4;
  const int chunk = blockIdx.x >> 5;
  const int tile  = blockIdx.x & 31;     // partners {tile+32k} share blockIdx%8

  // ---- XCD-affinity check, 2 rounds [R7 exact] ----
  unsigned xcc;
  asm volatile("s_getreg_b32 %0, hwreg(HW_REG_XCC_ID)" : "=s"(xcc));
  bool fast;
  {
    volatile unsigned* xs = (volatile unsigned*)(smem + WM_OFF);
    if (tid == 0) AG_ST(flags + (tile*8 + chunk)*16 + 8, 1u + xcc);
    if (tid < 8){
      unsigned v; long g = 0;
      do { v = AG_LD(flags + (tile*8 + tid)*16 + 8); } while (v == 0 && ++g < 10000000L);
      xs[tid] = v;
    }
    __syncthreads();
    unsigned ok = 1;
    #pragma unroll
    for (int j = 0; j < 8; ++j) ok &= (xs[j] == 1u + xcc) ? 1u : 0u;
    __syncthreads();
    if (tid == 0) AG_ST(flags + (tile*8 + chunk)*16 + 9, ok ? 2u : 1u);
    if (tid < 8){
      unsigned v; long g = 0;
      do { v = AG_LD(flags + (tile*8 + tid)*16 + 9); } while (v == 0 && ++g < 10000000L);
      xs[tid] = v;
    }
    __syncthreads();
    unsigned all2 = 1;
    #pragma unroll
    for (int j = 0; j < 8; ++j) all2 &= (xs[j] == 2u) ? 1u : 0u;
    fast = (all2 != 0);
    __syncthreads();
  }

  // ---- register-resident W fragments [R7 exact] ----
  bf16x8 wf[4][12];
  #pragma unroll
  for (int ni = 0; ni < 4; ++ni){
    const int rowg = ni*256 + chunk*32 + hf*16 + lc;
    #pragma unroll
    for (int kf = 0; kf < 12; ++kf){
      const int k0 = kf*32 + lg*8;
      const float* src = (k0 < 128) ? (Wih + rowg*128 + k0)
                                    : (Whh + rowg*256 + (k0 - 128));
      f32x4 s0 = *(const f32x4*)(src);
      f32x4 s1 = *(const f32x4*)(src + 4);
      bf16x8 v;
      v[0]=(short)f2bf(s0[0]); v[1]=(short)f2bf(s0[1]);
      v[2]=(short)f2bf(s0[2]); v[3]=(short)f2bf(s0[3]);
      v[4]=(short)f2bf(s1[0]); v[5]=(short)f2bf(s1[1]);
      v[6]=(short)f2bf(s1[2]); v[7]=(short)f2bf(s1[3]);
      wf[ni][kf] = v;
    }
  }
  float bias[4];
  #pragma unroll
  for (int ni = 0; ni < 4; ++ni){
    const int rowg = ni*256 + chunk*32 + hf*16 + lc;
    bias[ni] = bih[rowg] + bhh[rowg];
  }

  // ---- LDS tables (PADDED: f -> f + (f>>4)*4) + tag step ----
  float* wm0 = (float*)(smem + WM_OFF);        // [160]
  float* wm1 = wm0 + 160;                      // [160]
  float* bem = wm0 + 320;                      // [160]
  if (tid < 128){
    float a = 0.f, b = 0.f, c = 0.f;
    if (tid < 126){ a = 4.0f*Wemb[tid]; b = 4.0f*Wemb[126 + tid]; c = Bemb[tid]; }
    const int pi = tid + (tid >> 4)*4;
    wm0[pi] = a; wm1[pi] = b; bem[pi] = c;
  }
  float* h1f = (float*)(smem + H1_OFF);
  float* c1f = (float*)(smem + C1_OFF);
  {
    const int j = tid;
    float gi  = Wih[(j      )*128 + 126] + bih[j      ] + bhh[j      ];
    float gg2 = Wih[(512 + j)*128 + 126] + bih[512 + j] + bhh[512 + j];
    float go  = Wih[(768 + j)*128 + 126] + bih[768 + j] + bhh[768 + j];
    float c1 = sigf(gi)*tanh_(gg2);
    h1f[j] = sigf(go)*tanh_(c1); c1f[j] = c1;
  }
  __syncthreads();

  // x-tile builder [R7 mapping; padded table reads]
  auto xtile = [&](int buf, float vx, float vy){
    const int row = tid >> 3;
    const int kf  = (tid & 7) >> 1;
    const int lgb = (tid & 1) * 2;
    const int c0  = kf*32 + lgb*8;             // 16-aligned
    const int cp  = c0 + (c0 >> 4)*4;          // padded base (distinct bank quads)
    f32x4 wa = *(const f32x4*)(wm0 + cp), wb = *(const f32x4*)(wm0 + cp + 4);
    f32x4 wc = *(const f32x4*)(wm1 + cp), wd = *(const f32x4*)(wm1 + cp + 4);
    f32x4 ba = *(const f32x4*)(bem + cp), bb = *(const f32x4*)(bem + cp + 4);
    f32x4 we = *(const f32x4*)(wm0 + cp + 8), wg = *(const f32x4*)(wm0 + cp + 12);
    f32x4 wh = *(const f32x4*)(wm1 + cp + 8), wi = *(const f32x4*)(wm1 + cp + 12);
    f32x4 bc = *(const f32x4*)(bem + cp + 8), bd = *(const f32x4*)(bem + cp + 12);
    bf16x8 v0, v1;
    #pragma unroll
    for (int i = 0; i < 4; ++i){
      v0[i]     = (short)f2bf(fmaxf(vx*wa[i] + vy*wc[i] + ba[i], 0.f));
      v0[4 + i] = (short)f2bf(fmaxf(vx*wb[i] + vy*wd[i] + bb[i], 0.f));
      v1[i]     = (short)f2bf(fmaxf(vx*we[i] + vy*wh[i] + bc[i], 0.f));
      v1[4 + i] = (short)f2bf(fmaxf(vx*wg[i] + vy*wi[i] + bd[i], 0.f));
    }
    char* p = smem + XT(buf) + kf*FRAGB + row*ROWB + lgb*16;
    *(bf16x8*)(p)      = v0;
    *(bf16x8*)(p + 16) = v1;
  };

  // gather mapping [R7 exact]
  const int gr = tid >> 3;
  const int gg = tid & 7;

  // c-state + h_tile[0] + x_tile[0]
  const int col = chunk*32 + hf*16 + lc;
  float cs[4];
  { float cv = c1f[col]; cs[0]=cv; cs[1]=cv; cs[2]=cv; cs[3]=cv; }
  {
    const int hc0 = gg*32;
    bf16x8 v0, v1, v2, v3;
    #pragma unroll
    for (int i = 0; i < 8; ++i){
      v0[i] = (short)f2bf(h1f[hc0 + i]);      v1[i] = (short)f2bf(h1f[hc0 + 8 + i]);
      v2[i] = (short)f2bf(h1f[hc0 + 16 + i]); v3[i] = (short)f2bf(h1f[hc0 + 24 + i]);
    }
    char* pb = smem + HT(0) + gg*FRAGB + gr*ROWB;
    *(bf16x8*)(pb) = v0; *(bf16x8*)(pb+16) = v1; *(bf16x8*)(pb+32) = v2; *(bf16x8*)(pb+48) = v3;
  }
  {
    const float* op = obs + (tile*32 + gr)*512;
    f32x2 p0 = *(const f32x2*)(op), p1 = *(const f32x2*)(op + 2);
    xtile(0, p1[0] - p0[0], p1[1] - p0[1]);
  }
  __syncthreads();

  float hv[4] = {0.f, 0.f, 0.f, 0.f};
  long guard = 0;
  const int prow = m*16 + lg*4;

  for (int t = 0; t < T_STEPS; ++t){
    const int cur = t & 1;
    float vx = 0.f, vy = 0.f;
    if (t < T_STEPS - 1){
      const float* op = obs + (tile*32 + gr)*512 + (t + 1)*2;
      f32x2 p0 = *(const f32x2*)(op), p1 = *(const f32x2*)(op + 2);
      vx = p1[0] - p0[0]; vy = p1[1] - p0[1];
    }
    // ---- MFMA [R7 exact] ----
    f32x4 acc0 = (f32x4){bias[0],bias[0],bias[0],bias[0]};
    f32x4 acc1 = (f32x4){bias[1],bias[1],bias[1],bias[1]};
    f32x4 acc2 = (f32x4){bias[2],bias[2],bias[2],bias[2]};
    f32x4 acc3 = (f32x4){bias[3],bias[3],bias[3],bias[3]};
    {
      const int rowA = m*16 + lc;
      #pragma unroll
      for (int kf = 0; kf < 12; ++kf){
        const char* pa = smem + ((kf < 4) ? (XT(cur) + kf*FRAGB)
                                          : (HT(cur) + (kf - 4)*FRAGB))
                              + rowA*ROWB + lg*16;
        bf16x8 a = *(const bf16x8*)pa;
        acc0 = __builtin_amdgcn_mfma_f32_16x16x32_bf16(a, wf[0][kf], acc0, 0, 0, 0);
        acc1 = __builtin_amdgcn_mfma_f32_16x16x32_bf16(a, wf[1][kf], acc1, 0, 0, 0);
        acc2 = __builtin_amdgcn_mfma_f32_16x16x32_bf16(a, wf[2][kf], acc2, 0, 0, 0);
        acc3 = __builtin_amdgcn_mfma_f32_16x16x32_bf16(a, wf[3][kf], acc3, 0, 0, 0);
      }
    }
    // ---- elementwise [R7 exact] ----
    #pragma unroll
    for (int r = 0; r < 4; ++r){
      cs[r] = sigf(acc1[r])*cs[r] + sigf(acc0[r])*tanh_(acc2[r]);
      hv[r] = sigf(acc3[r])*tanh_(cs[r]);
    }

    if (t < T_STEPS - 1){
      const int slot = (t + 1) & 1;
      const unsigned want = ((unsigned)(t + 1)) << 16;

      // ---- publish own chunk (tagged) — SYSTEM SCOPE sc0 sc1 ----
      {
        unsigned w0 = want | f2bf(hv[0]);
        unsigned w1 = want | f2bf(hv[1]);
        unsigned w2 = want | f2bf(hv[2]);
        unsigned w3 = want | f2bf(hv[3]);
        unsigned int* dst = hbuf + slot*262144 + tile*8192 + prow*256 + col;
        if (fast){
          asm volatile("global_store_dword %0, %1, off sc0 sc1\n\t"
                       "global_store_dword %0, %2, off offset:1024 sc0 sc1\n\t"
                       "global_store_dword %0, %3, off offset:2048 sc0 sc1\n\t"
                       "global_store_dword %0, %4, off offset:3072 sc0 sc1"
                       :: "v"(dst), "v"(w0), "v"(w1), "v"(w2), "v"(w3) : "memory");
        } else {
          AG_ST(dst, w0); AG_ST(dst + 256, w1); AG_ST(dst + 512, w2); AG_ST(dst + 768, w3);
        }
      }

      xtile(slot, vx, vy);               // overlaps partners' publish flight

      // ---- probe-first spin on ONE 4B tag word — sc0 sc1 ----
      const unsigned int* src = hbuf + slot*262144 + tile*8192 + gr*256 + gg*32;
      {
        unsigned pv;
        do {
          if (fast){
            asm volatile("global_load_dword %0, %1, off sc0 sc1\n\t"
                         "s_waitcnt vmcnt(0)"
                         : "=&v"(pv) : "v"(src) : "memory");
          } else {
            pv = AG_LD(src);
          }
          if (((pv ^ want) & 0xffff0000u) == 0) break;
          __builtin_amdgcn_s_sleep(1);
        } while (++guard < 2000000L);
      }

      // ---- full tagged gather with retry — sc0 sc1 ----
      {
        u32x4 q0, q1, q2, q3, q4, q5, q6, q7;
        unsigned bad;
        do {
          if (fast){
            asm volatile(
              "global_load_dwordx4 %0, %8, off sc0 sc1\n\t"
              "global_load_dwordx4 %1, %8, off offset:16 sc0 sc1\n\t"
              "global_load_dwordx4 %2, %8, off offset:32 sc0 sc1\n\t"
              "global_load_dwordx4 %3, %8, off offset:48 sc0 sc1\n\t"
              "global_load_dwordx4 %4, %8, off offset:64 sc0 sc1\n\t"
              "global_load_dwordx4 %5, %8, off offset:80 sc0 sc1\n\t"
              "global_load_dwordx4 %6, %8, off offset:96 sc0 sc1\n\t"
              "global_load_dwordx4 %7, %8, off offset:112 sc0 sc1\n\t"
              "s_waitcnt vmcnt(0)"
              : "=&v"(q0), "=&v"(q1), "=&v"(q2), "=&v"(q3),
                "=&v"(q4), "=&v"(q5), "=&v"(q6), "=&v"(q7)
              : "v"(src) : "memory");
          } else {
            #pragma unroll
            for (int i = 0; i < 4; ++i){
              q0[i] = AG_LD(src +      i); q1[i] = AG_LD(src +  4 + i);
              q2[i] = AG_LD(src +  8 + i); q3[i] = AG_LD(src + 12 + i);
              q4[i] = AG_LD(src + 16 + i); q5[i] = AG_LD(src + 20 + i);
              q6[i] = AG_LD(src + 24 + i); q7[i] = AG_LD(src + 28 + i);
            }
          }
          bad = 0;
          #pragma unroll
          for (int i = 0; i < 4; ++i){
            bad |= (q0[i] ^ want) & 0xffff0000u; bad |= (q1[i] ^ want) & 0xffff0000u;
            bad |= (q2[i] ^ want) & 0xffff0000u; bad |= (q3[i] ^ want) & 0xffff0000u;
            bad |= (q4[i] ^ want) & 0xffff0000u; bad |= (q5[i] ^ want) & 0xffff0000u;
            bad |= (q6[i] ^ want) & 0xffff0000u; bad |= (q7[i] ^ want) & 0xffff0000u;
          }
        } while (bad && ++guard < 2000000L);

        bf16x8 v0, v1, v2, v3;
        #pragma unroll
        for (int i = 0; i < 4; ++i){
          v0[i] = (short)(q0[i] & 0xffffu); v0[4+i] = (short)(q1[i] & 0xffffu);
          v1[i] = (short)(q2[i] & 0xffffu); v1[4+i] = (short)(q3[i] & 0xffffu);
          v2[i] = (short)(q4[i] & 0xffffu); v2[4+i] = (short)(q5[i] & 0xffffu);
          v3[i] = (short)(q6[i] & 0xffffu); v3[4+i] = (short)(q7[i] & 0xffffu);
        }
        char* pb = smem + HT(slot) + gg*FRAGB + gr*ROWB;
        *(bf16x8*)(pb) = v0; *(bf16x8*)(pb+16) = v1; *(bf16x8*)(pb+32) = v2; *(bf16x8*)(pb+48) = v3;
      }
    }
    __syncthreads();
  }

  // ---- done-rendezvous before epilogue overwrites hbuf slot0 [R7 exact] ----
  if (tid == 0) AG_ST(flags + (tile*8 + chunk)*16 + 10, 1u);
  if (tid < 8){
    unsigned v; long g = 0;
    do { v = AG_LD(flags + (tile*8 + tid)*16 + 10); } while (v == 0 && ++g < 10000000L);
  }
  __syncthreads();

  // ---- epilogue [R7 exact] ----
  {
    const int row0 = tile*32 + prow;
    #pragma unroll
    for (int r = 0; r < 4; ++r){
      out[(row0 + r)*256 + col]          = hv[r];
      out[262144 + (row0 + r)*256 + col] = cs[r];
    }
  }
}

extern "C" void kernel_launch(void* const* d_in, const int* in_sizes, int n_in,
                              void* d_out, int out_size, void* d_ws, size_t ws_size,
                              hipStream_t stream) {
  (void)in_sizes; (void)n_in; (void)out_size; (void)ws_size;
  const float* obs  = (const float*)d_in[0];
  /* d_in[1] = pooled: unused */
  const float* Wemb = (const float*)d_in[2];
  const float* Bemb = (const float*)d_in[3];
  const float* Wih  = (const float*)d_in[4];
  const float* Whh  = (const float*)d_in[5];
  const float* bih  = (const float*)d_in[6];
  const float* bhh  = (const float*)d_in[7];
  float* out = (float*)d_out;
  unsigned int* flags = (unsigned int*)d_ws;        // 64KB: xcd/rendezvous words
  unsigned int* hbuf  = (unsigned int*)d_out;       // tagged exchange lives in d_out

  zero_ws<<<dim3(1056), dim3(512), 0, stream>>>(flags, hbuf);
  lstm_k<<<dim3(256), dim3(256), 0, stream>>>(obs, Wemb, Bemb, Wih, Whh, bih, bhh,
                                              out, flags, hbuf);
}

// Round 9
// 637.892 us; speedup vs baseline: 1.7559x; 1.7559x over previous
//
#include <hip/hip_runtime.h>
#include <stdint.h>

// LSTM_49357764165950 — MI355X (gfx950), round 9
// RESTRUCTURE (R1/R2/R4/R7/R8 all ~4us/step regardless of exchange protocol =>
// the wall was 1 wave/SIMD execution shape, not the exchange):
//   Grid 128 = 64 batch-tiles(16 rows) x 2 H-halves. Block 512 thr = 8 waves (2/SIMD).
//   Wave w: 16 h-cols x 4 gates, full K=384 -> 48 MFMA/wave, wf[4][12]=192 VGPR,
//   __launch_bounds__(512,2). Per SIMD/step: 96 MFMAs (~1870cy) -> compute-dominated.
//   Exchange degree = 2 (partner = blockIdx ^ 64; delta 64 == 0 mod 8 -> same XCD,
//   runtime-verified, agent-atomic fallback). R7-verbatim tagged-word protocol:
//   publish 4 tagged words (sc0) -> xtile -> probe 1 word -> full gather w/ tag-retry
//   (own cols gathered too -- uniform, no own-skip). One __syncthreads per step.
//   hbuf aliases d_out (2 slots x 64 tiles x 16x256 words = 2MB = d_out exactly).
//
// Slot-reuse safety (2 slots, R4 chain, degree 2): a block overwrites slot s with tag
// t+2 only after its gather of t+1 succeeded => partner published t+1 => partner passed
// its end-of-iter-(t-1) barrier => partner's slot-s reads (tag t) are complete.

typedef float  f32x4  __attribute__((ext_vector_type(4)));
typedef float  f32x2  __attribute__((ext_vector_type(2)));
typedef short  bf16x8 __attribute__((ext_vector_type(8)));
typedef short  bf16x4 __attribute__((ext_vector_type(4)));
typedef unsigned int u32x4 __attribute__((ext_vector_type(4)));

#define T_STEPS 255
#define ROWB    80                      // bytes per 32-col bf16 row (64B data + 16B pad)
#define FRAGB   1296                    // 16 rows * 80B + 16B pad (324 dw = 4 mod 32)
#define XT(b)   ((b)*4*FRAGB)           // x frags kf 0..3   (0, 5184)
#define HT(b)   (10368 + (b)*8*FRAGB)   // h frags 0..7      (10368, 20736; end 31104)
#define WM_OFF  31104                   // wm0p[160] wm1p[160] bemp[160] f32 (+xs scratch)
#define H1_OFF  33024                   // h1f[256] f32
#define C1_OFF  34048                   // c1f[256] f32
#define SMEM_SZ 36864

#define AG_ST(p, v) __hip_atomic_store((p), (v), __ATOMIC_RELAXED, __HIP_MEMORY_SCOPE_AGENT)
#define AG_LD(p)    __hip_atomic_load((p),        __ATOMIC_RELAXED, __HIP_MEMORY_SCOPE_AGENT)

__device__ __forceinline__ unsigned short f2bf(float f){
  union { float f; unsigned int u; } v; v.f = f;
  unsigned int u = v.u;
  return (unsigned short)((u + 0x7fffu + ((u >> 16) & 1u)) >> 16);   // RTNE
}
__device__ __forceinline__ float sigf(float x){
  float e = __builtin_amdgcn_exp2f(-1.4426950408889634f * x);
  return __builtin_amdgcn_rcpf(1.0f + e);
}
__device__ __forceinline__ float tanh_(float x){
  float e = __builtin_amdgcn_exp2f(-2.8853900817779268f * x);
  return (1.0f - e) * __builtin_amdgcn_rcpf(1.0f + e);
}

__global__ void zero_ws(unsigned int* flags, unsigned int* outw){
  const unsigned idx = blockIdx.x*512u + threadIdx.x;
  if (idx < 16384u)        AG_ST(flags + idx, 0u);
  else if (idx < 540672u)  AG_ST(outw + (idx - 16384u), 0u);
}

__global__ void __launch_bounds__(512, 2)
lstm_k(const float* __restrict__ obs,
       const float* __restrict__ Wemb, const float* __restrict__ Bemb,
       const float* __restrict__ Wih,  const float* __restrict__ Whh,
       const float* __restrict__ bih,  const float* __restrict__ bhh,
       float* out, unsigned int* flags, unsigned int* hbuf)   // hbuf aliases out
{
  __shared__ __align__(16) char smem[SMEM_SZ];
  const int tid = threadIdx.x;
  const int l   = tid & 63;
  const int w   = tid >> 6;            // wave 0..7: 16 h-cols each
  const int lc  = l & 15;
  const int lg  = l >> 4;
  const int T   = blockIdx.x & 63;     // batch tile (16 rows)
  const int tau = blockIdx.x >> 6;     // H-half 0/1; partner = blockIdx ^ 64 (same XCD)

  // ---- XCD-affinity check, 2 rounds, degree 2 [R7 protocol] ----
  unsigned xcc;
  asm volatile("s_getreg_b32 %0, hwreg(HW_REG_XCC_ID)" : "=s"(xcc));
  bool fast;
  {
    volatile unsigned* xs = (volatile unsigned*)(smem + WM_OFF);
    if (tid == 0) AG_ST(flags + (T*2 + tau)*16 + 8, 1u + xcc);
    if (tid < 2){
      unsigned v; long g = 0;
      do { v = AG_LD(flags + (T*2 + tid)*16 + 8); } while (v == 0 && ++g < 10000000L);
      xs[tid] = v;
    }
    __syncthreads();
    unsigned ok = (xs[0] == 1u + xcc && xs[1] == 1u + xcc) ? 1u : 0u;
    __syncthreads();
    if (tid == 0) AG_ST(flags + (T*2 + tau)*16 + 9, ok ? 2u : 1u);
    if (tid < 2){
      unsigned v; long g = 0;
      do { v = AG_LD(flags + (T*2 + tid)*16 + 9); } while (v == 0 && ++g < 10000000L);
      xs[tid] = v;
    }
    __syncthreads();
    fast = (xs[0] == 2u && xs[1] == 2u);
    __syncthreads();                       // before WM area reuse
  }

  // ---- register-resident W fragments: 4 gates x 12 K-frags for 16 own h-cols ----
  bf16x8 wf[4][12];
  #pragma unroll
  for (int g = 0; g < 4; ++g){
    const int rowg = g*256 + tau*128 + w*16 + lc;
    #pragma unroll
    for (int kf = 0; kf < 12; ++kf){
      const int k0 = kf*32 + lg*8;
      const float* src = (k0 < 128) ? (Wih + rowg*128 + k0)
                                    : (Whh + rowg*256 + (k0 - 128));
      f32x4 s0 = *(const f32x4*)(src);
      f32x4 s1 = *(const f32x4*)(src + 4);
      bf16x8 v;
      v[0]=(short)f2bf(s0[0]); v[1]=(short)f2bf(s0[1]);
      v[2]=(short)f2bf(s0[2]); v[3]=(short)f2bf(s0[3]);
      v[4]=(short)f2bf(s1[0]); v[5]=(short)f2bf(s1[1]);
      v[6]=(short)f2bf(s1[2]); v[7]=(short)f2bf(s1[3]);
      wf[g][kf] = v;
    }
  }
  float bias[4];
  #pragma unroll
  for (int g = 0; g < 4; ++g){
    const int rowg = g*256 + tau*128 + w*16 + lc;
    bias[g] = bih[rowg] + bhh[rowg];
  }

  // ---- LDS tables (padded pi = f + (f>>4)*4) + tag step [R8 exact] ----
  float* wm0 = (float*)(smem + WM_OFF);        // [160]
  float* wm1 = wm0 + 160;
  float* bem = wm0 + 320;
  if (tid < 128){
    float a = 0.f, b = 0.f, c = 0.f;
    if (tid < 126){ a = 4.0f*Wemb[tid]; b = 4.0f*Wemb[126 + tid]; c = Bemb[tid]; }
    const int pi = tid + (tid >> 4)*4;
    wm0[pi] = a; wm1[pi] = b; bem[pi] = c;
  }
  float* h1f = (float*)(smem + H1_OFF);
  float* c1f = (float*)(smem + C1_OFF);
  if (tid < 256){
    const int j = tid;
    float gi  = Wih[(j      )*128 + 126] + bih[j      ] + bhh[j      ];
    float gg2 = Wih[(512 + j)*128 + 126] + bih[512 + j] + bhh[512 + j];
    float go  = Wih[(768 + j)*128 + 126] + bih[768 + j] + bhh[768 + j];
    float c1 = sigf(gi)*tanh_(gg2);
    h1f[j] = sigf(go)*tanh_(c1); c1f[j] = c1;
  }
  __syncthreads();

  // x-tile builder: 512 thr -> row = tid>>5 (16), 4 cols each
  auto xtile = [&](int buf, float vx, float vy){
    const int row = tid >> 5;
    const int cb  = (tid & 31) * 4;            // 0..124
    const int cp  = cb + (cb >> 4)*4;          // padded table index
    f32x4 wa = *(const f32x4*)(wm0 + cp);
    f32x4 wc = *(const f32x4*)(wm1 + cp);
    f32x4 ba = *(const f32x4*)(bem + cp);
    bf16x4 v;
    #pragma unroll
    for (int i = 0; i < 4; ++i)
      v[i] = (short)f2bf(fmaxf(vx*wa[i] + vy*wc[i] + ba[i], 0.f));
    *(bf16x4*)(smem + XT(buf) + (cb >> 5)*FRAGB + row*ROWB + (cb & 31)*2) = v;
  };

  // gather mapping: thread -> (row gr, 8 cols at c8)
  const int gr = tid >> 5;                     // 0..15
  const int c8 = (tid & 31) * 8;               // 0..248

  // c-state + h_tile[0] + x_tile[0]
  const int col = tau*128 + w*16 + lc;         // own global h-col
  float cs[4];
  { float cv = c1f[col]; cs[0]=cv; cs[1]=cv; cs[2]=cv; cs[3]=cv; }
  {
    bf16x8 v;
    #pragma unroll
    for (int i = 0; i < 8; ++i) v[i] = (short)f2bf(h1f[c8 + i]);
    *(bf16x8*)(smem + HT(0) + (c8 >> 5)*FRAGB + gr*ROWB + (c8 & 31)*2) = v;
  }
  {
    const float* op = obs + (T*16 + (tid >> 5))*512;
    f32x2 p0 = *(const f32x2*)(op), p1 = *(const f32x2*)(op + 2);
    xtile(0, p1[0] - p0[0], p1[1] - p0[1]);
  }
  __syncthreads();

  float hv[4] = {0.f, 0.f, 0.f, 0.f};
  long guard = 0;
  const int prow = lg*4;                       // first of this lane's 4 batch rows

  for (int t = 0; t < T_STEPS; ++t){
    const int cur = t & 1;
    float vx = 0.f, vy = 0.f;
    if (t < T_STEPS - 1){
      const float* op = obs + (T*16 + (tid >> 5))*512 + (t + 1)*2;
      f32x2 p0 = *(const f32x2*)(op), p1 = *(const f32x2*)(op + 2);
      vx = p1[0] - p0[0]; vy = p1[1] - p0[1];
    }
    // ---- MFMA: 16 rows x (16 cols x 4 gates), K=384 -> 48 MFMAs ----
    f32x4 acc0 = (f32x4){bias[0],bias[0],bias[0],bias[0]};
    f32x4 acc1 = (f32x4){bias[1],bias[1],bias[1],bias[1]};
    f32x4 acc2 = (f32x4){bias[2],bias[2],bias[2],bias[2]};
    f32x4 acc3 = (f32x4){bias[3],bias[3],bias[3],bias[3]};
    {
      const int rowA = lc;
      #pragma unroll
      for (int kf = 0; kf < 12; ++kf){
        const char* pa = smem + ((kf < 4) ? (XT(cur) + kf*FRAGB)
                                          : (HT(cur) + (kf - 4)*FRAGB))
                              + rowA*ROWB + lg*16;
        bf16x8 a = *(const bf16x8*)pa;
        acc0 = __builtin_amdgcn_mfma_f32_16x16x32_bf16(a, wf[0][kf], acc0, 0, 0, 0);
        acc1 = __builtin_amdgcn_mfma_f32_16x16x32_bf16(a, wf[1][kf], acc1, 0, 0, 0);
        acc2 = __builtin_amdgcn_mfma_f32_16x16x32_bf16(a, wf[2][kf], acc2, 0, 0, 0);
        acc3 = __builtin_amdgcn_mfma_f32_16x16x32_bf16(a, wf[3][kf], acc3, 0, 0, 0);
      }
    }
    // ---- elementwise (C-layout: reg r -> row lg*4+r, col lc) ----
    #pragma unroll
    for (int r = 0; r < 4; ++r){
      cs[r] = sigf(acc1[r])*cs[r] + sigf(acc0[r])*tanh_(acc2[r]);
      hv[r] = sigf(acc3[r])*tanh_(cs[r]);
    }

    if (t < T_STEPS - 1){
      const int slot = (t + 1) & 1;
      const unsigned want = ((unsigned)(t + 1)) << 16;

      // ---- publish own 16x16 chunk (4 tagged words/lane) [R7 shape] ----
      {
        unsigned w0 = want | f2bf(hv[0]);
        unsigned w1 = want | f2bf(hv[1]);
        unsigned w2 = want | f2bf(hv[2]);
        unsigned w3 = want | f2bf(hv[3]);
        unsigned int* dst = hbuf + slot*262144 + T*4096 + prow*256 + col;
        if (fast){
          asm volatile("global_store_dword %0, %1, off sc0\n\t"
                       "global_store_dword %0, %2, off offset:1024 sc0\n\t"
                       "global_store_dword %0, %3, off offset:2048 sc0\n\t"
                       "global_store_dword %0, %4, off offset:3072 sc0"
                       :: "v"(dst), "v"(w0), "v"(w1), "v"(w2), "v"(w3) : "memory");
        } else {
          AG_ST(dst, w0); AG_ST(dst + 256, w1); AG_ST(dst + 512, w2); AG_ST(dst + 768, w3);
        }
      }

      xtile(slot, vx, vy);               // overlaps publish flight

      // ---- probe-first spin on ONE 4B tag word [R7] ----
      const unsigned int* src = hbuf + slot*262144 + T*4096 + gr*256 + c8;
      {
        unsigned pv;
        do {
          if (fast){
            asm volatile("global_load_dword %0, %1, off sc0 nt\n\t"
                         "s_waitcnt vmcnt(0)"
                         : "=&v"(pv) : "v"(src) : "memory");
          } else {
            pv = AG_LD(src);
          }
          if (((pv ^ want) & 0xffff0000u) == 0) break;
          __builtin_amdgcn_s_sleep(1);
        } while (++guard < 2000000L);
      }

      // ---- full tagged gather (8 words) with retry [R7 semantics] ----
      {
        u32x4 q0, q1;
        unsigned bad;
        do {
          if (fast){
            asm volatile("global_load_dwordx4 %0, %2, off sc0 nt\n\t"
                         "global_load_dwordx4 %1, %2, off offset:16 sc0 nt\n\t"
                         "s_waitcnt vmcnt(0)"
                         : "=&v"(q0), "=&v"(q1) : "v"(src) : "memory");
          } else {
            #pragma unroll
            for (int i = 0; i < 4; ++i){
              q0[i] = AG_LD(src + i); q1[i] = AG_LD(src + 4 + i);
            }
          }
          bad = 0;
          #pragma unroll
          for (int i = 0; i < 4; ++i){
            bad |= (q0[i] ^ want) & 0xffff0000u;
            bad |= (q1[i] ^ want) & 0xffff0000u;
          }
        } while (bad && ++guard < 2000000L);

        bf16x8 v;
        #pragma unroll
        for (int i = 0; i < 4; ++i){
          v[i]     = (short)(q0[i] & 0xffffu);
          v[4 + i] = (short)(q1[i] & 0xffffu);
        }
        *(bf16x8*)(smem + HT(slot) + (c8 >> 5)*FRAGB + gr*ROWB + (c8 & 31)*2) = v;
      }
    }
    __syncthreads();                     // the ONE barrier per step
  }

  // ---- done-rendezvous (degree 2) before epilogue overwrites hbuf ----
  if (tid == 0) AG_ST(flags + (T*2 + tau)*16 + 10, 1u);
  if (tid < 2){
    unsigned v; long g = 0;
    do { v = AG_LD(flags + (T*2 + tid)*16 + 10); } while (v == 0 && ++g < 10000000L);
  }
  __syncthreads();

  // ---- epilogue: final (h, c) f32 ----
  {
    const int row0 = T*16 + prow;
    #pragma unroll
    for (int r = 0; r < 4; ++r){
      out[(row0 + r)*256 + col]          = hv[r];
      out[262144 + (row0 + r)*256 + col] = cs[r];
    }
  }
}

extern "C" void kernel_launch(void* const* d_in, const int* in_sizes, int n_in,
                              void* d_out, int out_size, void* d_ws, size_t ws_size,
                              hipStream_t stream) {
  (void)in_sizes; (void)n_in; (void)out_size; (void)ws_size;
  const float* obs  = (const float*)d_in[0];
  /* d_in[1] = pooled: unused */
  const float* Wemb = (const float*)d_in[2];
  const float* Bemb = (const float*)d_in[3];
  const float* Wih  = (const float*)d_in[4];
  const float* Whh  = (const float*)d_in[5];
  const float* bih  = (const float*)d_in[6];
  const float* bhh  = (const float*)d_in[7];
  float* out = (float*)d_out;
  unsigned int* flags = (unsigned int*)d_ws;        // 64KB: xcd/rendezvous words
  unsigned int* hbuf  = (unsigned int*)d_out;       // tagged exchange lives in d_out

  zero_ws<<<dim3(1056), dim3(512), 0, stream>>>(flags, hbuf);
  lstm_k<<<dim3(128), dim3(512), 0, stream>>>(obs, Wemb, Bemb, Wih, Whh, bih, bhh,
                                              out, flags, hbuf);
}

// Round 10
// 551.814 us; speedup vs baseline: 2.0298x; 1.1560x over previous
//
#include <hip/hip_runtime.h>
#include <stdint.h>

// LSTM_49357764165950 — MI355X (gfx950), round 10
// R9 (638us) used only 128 CUs. R10 fills 256 CUs keeping R9's winning shape
// (8-wave blocks = 2 waves/SIMD; tagged-word exchange; one gather/step):
//   Grid 256 = 64 batch-tiles T (16 rows) x 4 H-quarters q (64 h-cols).
//   Block 512 thr = 8 waves: w = hsub + 4*kh. Wave: 4 gates x 16 h-cols x K-half
//   (192 = 6 kf) -> 24 MFMA, wf[4][6] = 96 VGPR. Per SIMD: 48 MFMA (~930cy).
//   K-halves summed via R1-proven LDS redbuf (f32x2 lane-major, conflict-free),
//   one extra barrier. kh=0 finalizes rows lg*4+{0,1}, kh=1 rows lg*4+{2,3}.
//   Exchange degree 4 (partners blockIdx = q*64+T, delta 64 == 0 mod 8 -> same XCD,
//   runtime-verified, agent fallback). R9-verbatim protocol: publish 2 tagged words
//   (sc0) -> xtile -> probe 1 word -> 8-word gather with tag-retry -> barrier.
//
// Slot-reuse safety (2 slots, R4 chain): a block overwrites slot s with tag t+2 only
// after its gather of t+1 succeeded => all partners published t+1 => they passed their
// end-of-iter-(t-1) barrier => their slot-s reads (tag t) are complete.

typedef float  f32x4  __attribute__((ext_vector_type(4)));
typedef float  f32x2  __attribute__((ext_vector_type(2)));
typedef short  bf16x8 __attribute__((ext_vector_type(8)));
typedef short  bf16x4 __attribute__((ext_vector_type(4)));
typedef unsigned int u32x4 __attribute__((ext_vector_type(4)));

#define T_STEPS 255
#define ROWB    80                      // bytes per 32-col bf16 row (64B data + 16B pad)
#define FRAGB   1296                    // 16 rows * 80B + 16B pad
#define XT(b)   ((b)*4*FRAGB)           // x frags kf 0..3   (0, 5184)
#define HT(b)   (10368 + (b)*8*FRAGB)   // h frags 0..7      (10368, 20736; end 31104)
#define RB_OFF  31104                   // redbuf [8 slots][4 gates][64] f32x2 = 16KB
#define WM_OFF  47488                   // wm0p[160] wm1p[160] bemp[160] f32 (+xs scratch)
#define H1_OFF  49408                   // h1f[256] f32
#define C1_OFF  50432                   // c1f[256] f32
#define SMEM_SZ 52224

#define AG_ST(p, v) __hip_atomic_store((p), (v), __ATOMIC_RELAXED, __HIP_MEMORY_SCOPE_AGENT)
#define AG_LD(p)    __hip_atomic_load((p),        __ATOMIC_RELAXED, __HIP_MEMORY_SCOPE_AGENT)

__device__ __forceinline__ unsigned short f2bf(float f){
  union { float f; unsigned int u; } v; v.f = f;
  unsigned int u = v.u;
  return (unsigned short)((u + 0x7fffu + ((u >> 16) & 1u)) >> 16);   // RTNE
}
__device__ __forceinline__ float sigf(float x){
  float e = __builtin_amdgcn_exp2f(-1.4426950408889634f * x);
  return __builtin_amdgcn_rcpf(1.0f + e);
}
__device__ __forceinline__ float tanh_(float x){
  float e = __builtin_amdgcn_exp2f(-2.8853900817779268f * x);
  return (1.0f - e) * __builtin_amdgcn_rcpf(1.0f + e);
}

__global__ void zero_ws(unsigned int* flags, unsigned int* outw){
  const unsigned idx = blockIdx.x*512u + threadIdx.x;
  if (idx < 16384u)        AG_ST(flags + idx, 0u);
  else if (idx < 540672u)  AG_ST(outw + (idx - 16384u), 0u);
}

__global__ void __launch_bounds__(512, 2)
lstm_k(const float* __restrict__ obs,
       const float* __restrict__ Wemb, const float* __restrict__ Bemb,
       const float* __restrict__ Wih,  const float* __restrict__ Whh,
       const float* __restrict__ bih,  const float* __restrict__ bhh,
       float* out, unsigned int* flags, unsigned int* hbuf)   // hbuf aliases out
{
  __shared__ __align__(16) char smem[SMEM_SZ];
  const int tid  = threadIdx.x;
  const int l    = tid & 63;
  const int w    = tid >> 6;           // 0..7
  const int hsub = w & 3;              // 16-col group within the quarter
  const int kh   = w >> 2;             // K-half
  const int lc   = l & 15;
  const int lg   = l >> 4;
  const int T    = blockIdx.x & 63;    // batch tile (16 rows)
  const int q    = blockIdx.x >> 6;    // H-quarter 0..3; partners delta=64 (same XCD)

  // ---- XCD-affinity check, 2 rounds, degree 4 [R9 protocol] ----
  unsigned xcc;
  asm volatile("s_getreg_b32 %0, hwreg(HW_REG_XCC_ID)" : "=s"(xcc));
  bool fast;
  {
    volatile unsigned* xs = (volatile unsigned*)(smem + WM_OFF);
    if (tid == 0) AG_ST(flags + (T*4 + q)*16 + 8, 1u + xcc);
    if (tid < 4){
      unsigned v; long g = 0;
      do { v = AG_LD(flags + (T*4 + tid)*16 + 8); } while (v == 0 && ++g < 10000000L);
      xs[tid] = v;
    }
    __syncthreads();
    unsigned ok = 1;
    #pragma unroll
    for (int j = 0; j < 4; ++j) ok &= (xs[j] == 1u + xcc) ? 1u : 0u;
    __syncthreads();
    if (tid == 0) AG_ST(flags + (T*4 + q)*16 + 9, ok ? 2u : 1u);
    if (tid < 4){
      unsigned v; long g = 0;
      do { v = AG_LD(flags + (T*4 + tid)*16 + 9); } while (v == 0 && ++g < 10000000L);
      xs[tid] = v;
    }
    __syncthreads();
    unsigned all2 = 1;
    #pragma unroll
    for (int j = 0; j < 4; ++j) all2 &= (xs[j] == 2u) ? 1u : 0u;
    fast = (all2 != 0);
    __syncthreads();                       // before WM area reuse
  }

  // ---- register-resident W fragments: 4 gates x 6 K-frags (own K-half) ----
  bf16x8 wf[4][6];
  #pragma unroll
  for (int g = 0; g < 4; ++g){
    const int rowg = g*256 + q*64 + hsub*16 + lc;
    #pragma unroll
    for (int kfl = 0; kfl < 6; ++kfl){
      const int k0 = (kh*6 + kfl)*32 + lg*8;
      const float* src = (k0 < 128) ? (Wih + rowg*128 + k0)
                                    : (Whh + rowg*256 + (k0 - 128));
      f32x4 s0 = *(const f32x4*)(src);
      f32x4 s1 = *(const f32x4*)(src + 4);
      bf16x8 v;
      v[0]=(short)f2bf(s0[0]); v[1]=(short)f2bf(s0[1]);
      v[2]=(short)f2bf(s0[2]); v[3]=(short)f2bf(s0[3]);
      v[4]=(short)f2bf(s1[0]); v[5]=(short)f2bf(s1[1]);
      v[6]=(short)f2bf(s1[2]); v[7]=(short)f2bf(s1[3]);
      wf[g][kfl] = v;
    }
  }
  float bias[4];
  #pragma unroll
  for (int g = 0; g < 4; ++g){
    const int rowg = g*256 + q*64 + hsub*16 + lc;
    bias[g] = (kh == 0) ? (bih[rowg] + bhh[rowg]) : 0.f;
  }

  // ---- LDS tables (padded pi = f + (f>>4)*4) + tag step [R9 exact] ----
  float* wm0 = (float*)(smem + WM_OFF);        // [160]
  float* wm1 = wm0 + 160;
  float* bem = wm0 + 320;
  if (tid < 128){
    float a = 0.f, b = 0.f, c = 0.f;
    if (tid < 126){ a = 4.0f*Wemb[tid]; b = 4.0f*Wemb[126 + tid]; c = Bemb[tid]; }
    const int pi = tid + (tid >> 4)*4;
    wm0[pi] = a; wm1[pi] = b; bem[pi] = c;
  }
  float* h1f = (float*)(smem + H1_OFF);
  float* c1f = (float*)(smem + C1_OFF);
  if (tid < 256){
    const int j = tid;
    float gi  = Wih[(j      )*128 + 126] + bih[j      ] + bhh[j      ];
    float gg2 = Wih[(512 + j)*128 + 126] + bih[512 + j] + bhh[512 + j];
    float go  = Wih[(768 + j)*128 + 126] + bih[768 + j] + bhh[768 + j];
    float c1 = sigf(gi)*tanh_(gg2);
    h1f[j] = sigf(go)*tanh_(c1); c1f[j] = c1;
  }
  __syncthreads();

  // x-tile builder [R9 exact]: row = tid>>5 (16 rows), 4 cols each
  auto xtile = [&](int buf, float vx, float vy){
    const int row = tid >> 5;
    const int cb  = (tid & 31) * 4;
    const int cp  = cb + (cb >> 4)*4;
    f32x4 wa = *(const f32x4*)(wm0 + cp);
    f32x4 wc = *(const f32x4*)(wm1 + cp);
    f32x4 ba = *(const f32x4*)(bem + cp);
    bf16x4 v;
    #pragma unroll
    for (int i = 0; i < 4; ++i)
      v[i] = (short)f2bf(fmaxf(vx*wa[i] + vy*wc[i] + ba[i], 0.f));
    *(bf16x4*)(smem + XT(buf) + (cb >> 5)*FRAGB + row*ROWB + (cb & 31)*2) = v;
  };

  // gather mapping [R9 exact]: thread -> (row gr, 8 cols at c8)
  const int gr = tid >> 5;
  const int c8 = (tid & 31) * 8;

  // c-state (2 rows/lane) + h_tile[0] + x_tile[0]
  const int col  = q*64 + hsub*16 + lc;        // own global h-col
  const int row0 = lg*4 + 2*kh;                // first of this lane's 2 finalized rows
  float cs0, cs1;
  { float cv = c1f[col]; cs0 = cv; cs1 = cv; }
  {
    bf16x8 v;
    #pragma unroll
    for (int i = 0; i < 8; ++i) v[i] = (short)f2bf(h1f[c8 + i]);
    *(bf16x8*)(smem + HT(0) + (c8 >> 5)*FRAGB + gr*ROWB + (c8 & 31)*2) = v;
  }
  {
    const float* op = obs + (T*16 + (tid >> 5))*512;
    f32x2 p0 = *(const f32x2*)(op), p1 = *(const f32x2*)(op + 2);
    xtile(0, p1[0] - p0[0], p1[1] - p0[1]);
  }
  __syncthreads();

  float hv0 = 0.f, hv1 = 0.f;
  long guard = 0;

  for (int t = 0; t < T_STEPS; ++t){
    const int cur = t & 1;
    float vx = 0.f, vy = 0.f;
    if (t < T_STEPS - 1){
      const float* op = obs + (T*16 + (tid >> 5))*512 + (t + 1)*2;
      f32x2 p0 = *(const f32x2*)(op), p1 = *(const f32x2*)(op + 2);
      vx = p1[0] - p0[0]; vy = p1[1] - p0[1];
    }
    // ---- MFMA: 16 rows x (16 cols x 4 gates), own K-half -> 24 MFMAs ----
    f32x4 acc0 = (f32x4){bias[0],bias[0],bias[0],bias[0]};
    f32x4 acc1 = (f32x4){bias[1],bias[1],bias[1],bias[1]};
    f32x4 acc2 = (f32x4){bias[2],bias[2],bias[2],bias[2]};
    f32x4 acc3 = (f32x4){bias[3],bias[3],bias[3],bias[3]};
    {
      const int rowA = lc;
      #pragma unroll
      for (int kfl = 0; kfl < 6; ++kfl){
        const int kfi = kh*6 + kfl;
        const char* pa = smem + ((kfi < 4) ? (XT(cur) + kfi*FRAGB)
                                           : (HT(cur) + (kfi - 4)*FRAGB))
                              + rowA*ROWB + lg*16;
        bf16x8 a = *(const bf16x8*)pa;
        acc0 = __builtin_amdgcn_mfma_f32_16x16x32_bf16(a, wf[0][kfl], acc0, 0, 0, 0);
        acc1 = __builtin_amdgcn_mfma_f32_16x16x32_bf16(a, wf[1][kfl], acc1, 0, 0, 0);
        acc2 = __builtin_amdgcn_mfma_f32_16x16x32_bf16(a, wf[2][kfl], acc2, 0, 0, 0);
        acc3 = __builtin_amdgcn_mfma_f32_16x16x32_bf16(a, wf[3][kfl], acc3, 0, 0, 0);
      }
    }
    // ---- redbuf export (partner's half) [R1-proven pattern] ----
    {
      f32x2* rb = (f32x2*)(smem + RB_OFF);
      const int sl = kh ^ 1;
      const int base = ((hsub*2 + sl)*4)*64 + l;
      f32x2 e0, e1, e2, e3;
      if (kh == 0){
        e0 = (f32x2){acc0[2], acc0[3]}; e1 = (f32x2){acc1[2], acc1[3]};
        e2 = (f32x2){acc2[2], acc2[3]}; e3 = (f32x2){acc3[2], acc3[3]};
      } else {
        e0 = (f32x2){acc0[0], acc0[1]}; e1 = (f32x2){acc1[0], acc1[1]};
        e2 = (f32x2){acc2[0], acc2[1]}; e3 = (f32x2){acc3[0], acc3[1]};
      }
      rb[base] = e0; rb[base + 64] = e1; rb[base + 128] = e2; rb[base + 192] = e3;
    }
    __syncthreads();                               // barrier #1 (K-reduce)
    // ---- K-reduce own half + LSTM elementwise (2 rows/lane) ----
    {
      f32x2* rb = (f32x2*)(smem + RB_OFF);
      const int base = ((hsub*2 + kh)*4)*64 + l;
      f32x2 r0 = rb[base], r1 = rb[base + 64], r2 = rb[base + 128], r3 = rb[base + 192];
      float gi0, gi1, gf0, gf1, gg0, gg1, go0, go1;
      if (kh == 0){
        gi0 = acc0[0] + r0[0]; gi1 = acc0[1] + r0[1];
        gf0 = acc1[0] + r1[0]; gf1 = acc1[1] + r1[1];
        gg0 = acc2[0] + r2[0]; gg1 = acc2[1] + r2[1];
        go0 = acc3[0] + r3[0]; go1 = acc3[1] + r3[1];
      } else {
        gi0 = acc0[2] + r0[0]; gi1 = acc0[3] + r0[1];
        gf0 = acc1[2] + r1[0]; gf1 = acc1[3] + r1[1];
        gg0 = acc2[2] + r2[0]; gg1 = acc2[3] + r2[1];
        go0 = acc3[2] + r3[0]; go1 = acc3[3] + r3[1];
      }
      cs0 = sigf(gf0)*cs0 + sigf(gi0)*tanh_(gg0);
      hv0 = sigf(go0)*tanh_(cs0);
      cs1 = sigf(gf1)*cs1 + sigf(gi1)*tanh_(gg1);
      hv1 = sigf(go1)*tanh_(cs1);
    }

    if (t < T_STEPS - 1){
      const int slot = (t + 1) & 1;
      const unsigned want = ((unsigned)(t + 1)) << 16;

      // ---- publish own 2 rows (tagged) [R9 protocol] ----
      {
        unsigned w0 = want | f2bf(hv0);
        unsigned w1 = want | f2bf(hv1);
        unsigned int* dst = hbuf + slot*262144 + T*4096 + row0*256 + col;
        if (fast){
          asm volatile("global_store_dword %0, %1, off sc0\n\t"
                       "global_store_dword %0, %2, off offset:1024 sc0"
                       :: "v"(dst), "v"(w0), "v"(w1) : "memory");
        } else {
          AG_ST(dst, w0); AG_ST(dst + 256, w1);
        }
      }

      xtile(slot, vx, vy);               // overlaps publish flight

      // ---- probe-first spin on ONE 4B tag word [R9] ----
      const unsigned int* src = hbuf + slot*262144 + T*4096 + gr*256 + c8;
      {
        unsigned pv;
        do {
          if (fast){
            asm volatile("global_load_dword %0, %1, off sc0 nt\n\t"
                         "s_waitcnt vmcnt(0)"
                         : "=&v"(pv) : "v"(src) : "memory");
          } else {
            pv = AG_LD(src);
          }
          if (((pv ^ want) & 0xffff0000u) == 0) break;
          __builtin_amdgcn_s_sleep(1);
        } while (++guard < 2000000L);
      }

      // ---- full tagged gather (8 words) with retry [R9 exact] ----
      {
        u32x4 q0, q1;
        unsigned bad;
        do {
          if (fast){
            asm volatile("global_load_dwordx4 %0, %2, off sc0 nt\n\t"
                         "global_load_dwordx4 %1, %2, off offset:16 sc0 nt\n\t"
                         "s_waitcnt vmcnt(0)"
                         : "=&v"(q0), "=&v"(q1) : "v"(src) : "memory");
          } else {
            #pragma unroll
            for (int i = 0; i < 4; ++i){
              q0[i] = AG_LD(src + i); q1[i] = AG_LD(src + 4 + i);
            }
          }
          bad = 0;
          #pragma unroll
          for (int i = 0; i < 4; ++i){
            bad |= (q0[i] ^ want) & 0xffff0000u;
            bad |= (q1[i] ^ want) & 0xffff0000u;
          }
        } while (bad && ++guard < 2000000L);

        bf16x8 v;
        #pragma unroll
        for (int i = 0; i < 4; ++i){
          v[i]     = (short)(q0[i] & 0xffffu);
          v[4 + i] = (short)(q1[i] & 0xffffu);
        }
        *(bf16x8*)(smem + HT(slot) + (c8 >> 5)*FRAGB + gr*ROWB + (c8 & 31)*2) = v;
      }
    }
    __syncthreads();                     // barrier #2 (end of step)
  }

  // ---- done-rendezvous (degree 4) before epilogue overwrites hbuf ----
  if (tid == 0) AG_ST(flags + (T*4 + q)*16 + 10, 1u);
  if (tid < 4){
    unsigned v; long g = 0;
    do { v = AG_LD(flags + (T*4 + tid)*16 + 10); } while (v == 0 && ++g < 10000000L);
  }
  __syncthreads();

  // ---- epilogue: final (h, c) f32 for this lane's 2 rows ----
  {
    const int r = T*16 + row0;
    out[r*256 + col]                = hv0;
    out[(r + 1)*256 + col]          = hv1;
    out[262144 + r*256 + col]       = cs0;
    out[262144 + (r + 1)*256 + col] = cs1;
  }
}

extern "C" void kernel_launch(void* const* d_in, const int* in_sizes, int n_in,
                              void* d_out, int out_size, void* d_ws, size_t ws_size,
                              hipStream_t stream) {
  (void)in_sizes; (void)n_in; (void)out_size; (void)ws_size;
  const float* obs  = (const float*)d_in[0];
  /* d_in[1] = pooled: unused */
  const float* Wemb = (const float*)d_in[2];
  const float* Bemb = (const float*)d_in[3];
  const float* Wih  = (const float*)d_in[4];
  const float* Whh  = (const float*)d_in[5];
  const float* bih  = (const float*)d_in[6];
  const float* bhh  = (const float*)d_in[7];
  float* out = (float*)d_out;
  unsigned int* flags = (unsigned int*)d_ws;        // 64KB: xcd/rendezvous words
  unsigned int* hbuf  = (unsigned int*)d_out;       // tagged exchange lives in d_out

  zero_ws<<<dim3(1056), dim3(512), 0, stream>>>(flags, hbuf);
  lstm_k<<<dim3(256), dim3(512), 0, stream>>>(obs, Wemb, Bemb, Wih, Whh, bih, bhh,
                                              out, flags, hbuf);
}

// Round 11
// 463.996 us; speedup vs baseline: 2.4140x; 1.1893x over previous
//
#include <hip/hip_runtime.h>
#include <stdint.h>

// LSTM_49357764165950 — MI355X (gfx950), round 11
// = R10 (552us, 256 CUs, 8 waves = 2/SIMD, K-half redbuf, tagged exchange) with the
// step SOFTWARE-PIPELINED so gather latency hides under x-part MFMA:
//   wave (hsub, kh): x-frags {2kh,2kh+1} (8 MFMA) + h-frags {4kh..4kh+3} (16 MFMA).
//   iter t: x-MFMA -> direct tagged gather of h_t (R4-verbatim retry, no probe) ->
//           h->LDS + xtile(t+1) -> barrier A -> h-MFMA -> redbuf export -> barrier B
//           -> K-reduce + elementwise -> publish h_{t+1}. No end-of-loop barrier.
// Ordering proofs:
//   * buffers double-alternate; B_t orders iter-t reads vs iter-(t+1) writes (all
//     iter-(t+1) LDS writes occur after A_{t+1} > B_t; x/h reads of iter t are
//     before A_t/B_t respectively).
//   * redbuf: iter-t reduce reads (after B_t) complete before any thread passes
//     A_{t+1}; iter-(t+1) exports write after A_{t+1}.
//   * 2-slot publish chain unchanged: publish@t+2 only after gather of t+2 succeeded
//     => partner passed B_{t+1} => partner's old-slot reads complete.

typedef float  f32x4  __attribute__((ext_vector_type(4)));
typedef float  f32x2  __attribute__((ext_vector_type(2)));
typedef short  bf16x8 __attribute__((ext_vector_type(8)));
typedef short  bf16x4 __attribute__((ext_vector_type(4)));
typedef unsigned int u32x4 __attribute__((ext_vector_type(4)));

#define T_STEPS 255
#define ROWB    80                      // bytes per 32-col bf16 row (64B data + 16B pad)
#define FRAGB   1296                    // 16 rows * 80B + 16B pad
#define XT(b)   ((b)*4*FRAGB)           // x frags kf 0..3   (0, 5184)
#define HT(b)   (10368 + (b)*8*FRAGB)   // h frags 0..7      (10368, 20736; end 31104)
#define RB_OFF  31104                   // redbuf [8 slots][4 gates][64] f32x2 = 16KB
#define WM_OFF  47488                   // wm0p[160] wm1p[160] bemp[160] f32 (+xs scratch)
#define H1_OFF  49408                   // h1f[256] f32
#define C1_OFF  50432                   // c1f[256] f32
#define SMEM_SZ 52224

#define AG_ST(p, v) __hip_atomic_store((p), (v), __ATOMIC_RELAXED, __HIP_MEMORY_SCOPE_AGENT)
#define AG_LD(p)    __hip_atomic_load((p),        __ATOMIC_RELAXED, __HIP_MEMORY_SCOPE_AGENT)

__device__ __forceinline__ unsigned short f2bf(float f){
  union { float f; unsigned int u; } v; v.f = f;
  unsigned int u = v.u;
  return (unsigned short)((u + 0x7fffu + ((u >> 16) & 1u)) >> 16);   // RTNE
}
__device__ __forceinline__ float sigf(float x){
  float e = __builtin_amdgcn_exp2f(-1.4426950408889634f * x);
  return __builtin_amdgcn_rcpf(1.0f + e);
}
__device__ __forceinline__ float tanh_(float x){
  float e = __builtin_amdgcn_exp2f(-2.8853900817779268f * x);
  return (1.0f - e) * __builtin_amdgcn_rcpf(1.0f + e);
}

__global__ void zero_ws(unsigned int* flags, unsigned int* outw){
  const unsigned idx = blockIdx.x*512u + threadIdx.x;
  if (idx < 16384u)        AG_ST(flags + idx, 0u);
  else if (idx < 540672u)  AG_ST(outw + (idx - 16384u), 0u);
}

__global__ void __launch_bounds__(512, 2)
lstm_k(const float* __restrict__ obs,
       const float* __restrict__ Wemb, const float* __restrict__ Bemb,
       const float* __restrict__ Wih,  const float* __restrict__ Whh,
       const float* __restrict__ bih,  const float* __restrict__ bhh,
       float* out, unsigned int* flags, unsigned int* hbuf)   // hbuf aliases out
{
  __shared__ __align__(16) char smem[SMEM_SZ];
  const int tid  = threadIdx.x;
  const int l    = tid & 63;
  const int w    = tid >> 6;           // 0..7
  const int hsub = w & 3;              // 16-col group within the quarter
  const int kh   = w >> 2;             // K-half
  const int lc   = l & 15;
  const int lg   = l >> 4;
  const int T    = blockIdx.x & 63;    // batch tile (16 rows)
  const int q    = blockIdx.x >> 6;    // H-quarter 0..3; partners delta=64 (same XCD)

  // ---- XCD-affinity check, 2 rounds, degree 4 [R10 exact] ----
  unsigned xcc;
  asm volatile("s_getreg_b32 %0, hwreg(HW_REG_XCC_ID)" : "=s"(xcc));
  bool fast;
  {
    volatile unsigned* xs = (volatile unsigned*)(smem + WM_OFF);
    if (tid == 0) AG_ST(flags + (T*4 + q)*16 + 8, 1u + xcc);
    if (tid < 4){
      unsigned v; long g = 0;
      do { v = AG_LD(flags + (T*4 + tid)*16 + 8); } while (v == 0 && ++g < 10000000L);
      xs[tid] = v;
    }
    __syncthreads();
    unsigned ok = 1;
    #pragma unroll
    for (int j = 0; j < 4; ++j) ok &= (xs[j] == 1u + xcc) ? 1u : 0u;
    __syncthreads();
    if (tid == 0) AG_ST(flags + (T*4 + q)*16 + 9, ok ? 2u : 1u);
    if (tid < 4){
      unsigned v; long g = 0;
      do { v = AG_LD(flags + (T*4 + tid)*16 + 9); } while (v == 0 && ++g < 10000000L);
      xs[tid] = v;
    }
    __syncthreads();
    unsigned all2 = 1;
    #pragma unroll
    for (int j = 0; j < 4; ++j) all2 &= (xs[j] == 2u) ? 1u : 0u;
    fast = (all2 != 0);
    __syncthreads();                       // before WM area reuse
  }

  // ---- register-resident W fragments: 4 gates x (2 x-frags + 4 h-frags) ----
  bf16x8 wf[4][6];
  #pragma unroll
  for (int g = 0; g < 4; ++g){
    const int rowg = g*256 + q*64 + hsub*16 + lc;
    #pragma unroll
    for (int kfl = 0; kfl < 6; ++kfl){
      const float* src;
      if (kfl < 2){
        const int k0 = (kh*2 + kfl)*32 + lg*8;           // x: global K 0..127
        src = Wih + rowg*128 + k0;
      } else {
        const int k0 = (kh*4 + kfl - 2)*32 + lg*8;       // h: 0..255
        src = Whh + rowg*256 + k0;
      }
      f32x4 s0 = *(const f32x4*)(src);
      f32x4 s1 = *(const f32x4*)(src + 4);
      bf16x8 v;
      v[0]=(short)f2bf(s0[0]); v[1]=(short)f2bf(s0[1]);
      v[2]=(short)f2bf(s0[2]); v[3]=(short)f2bf(s0[3]);
      v[4]=(short)f2bf(s1[0]); v[5]=(short)f2bf(s1[1]);
      v[6]=(short)f2bf(s1[2]); v[7]=(short)f2bf(s1[3]);
      wf[g][kfl] = v;
    }
  }
  float bias[4];
  #pragma unroll
  for (int g = 0; g < 4; ++g){
    const int rowg = g*256 + q*64 + hsub*16 + lc;
    bias[g] = (kh == 0) ? (bih[rowg] + bhh[rowg]) : 0.f;
  }

  // ---- LDS tables (padded pi = f + (f>>4)*4) + tag step [R10 exact] ----
  float* wm0 = (float*)(smem + WM_OFF);        // [160]
  float* wm1 = wm0 + 160;
  float* bem = wm0 + 320;
  if (tid < 128){
    float a = 0.f, b = 0.f, c = 0.f;
    if (tid < 126){ a = 4.0f*Wemb[tid]; b = 4.0f*Wemb[126 + tid]; c = Bemb[tid]; }
    const int pi = tid + (tid >> 4)*4;
    wm0[pi] = a; wm1[pi] = b; bem[pi] = c;
  }
  float* h1f = (float*)(smem + H1_OFF);
  float* c1f = (float*)(smem + C1_OFF);
  if (tid < 256){
    const int j = tid;
    float gi  = Wih[(j      )*128 + 126] + bih[j      ] + bhh[j      ];
    float gg2 = Wih[(512 + j)*128 + 126] + bih[512 + j] + bhh[512 + j];
    float go  = Wih[(768 + j)*128 + 126] + bih[768 + j] + bhh[768 + j];
    float c1 = sigf(gi)*tanh_(gg2);
    h1f[j] = sigf(go)*tanh_(c1); c1f[j] = c1;
  }
  __syncthreads();

  // x-tile builder [R10 exact]
  auto xtile = [&](int buf, float vx, float vy){
    const int row = tid >> 5;
    const int cb  = (tid & 31) * 4;
    const int cp  = cb + (cb >> 4)*4;
    f32x4 wa = *(const f32x4*)(wm0 + cp);
    f32x4 wc = *(const f32x4*)(wm1 + cp);
    f32x4 ba = *(const f32x4*)(bem + cp);
    bf16x4 v;
    #pragma unroll
    for (int i = 0; i < 4; ++i)
      v[i] = (short)f2bf(fmaxf(vx*wa[i] + vy*wc[i] + ba[i], 0.f));
    *(bf16x4*)(smem + XT(buf) + (cb >> 5)*FRAGB + row*ROWB + (cb & 31)*2) = v;
  };

  // gather mapping [R10 exact]
  const int gr = tid >> 5;
  const int c8 = (tid & 31) * 8;

  // c-state (2 rows/lane) + h_tile[0] + x_tile[0]
  const int col  = q*64 + hsub*16 + lc;
  const int row0 = lg*4 + 2*kh;
  float cs0, cs1;
  { float cv = c1f[col]; cs0 = cv; cs1 = cv; }
  {
    bf16x8 v;
    #pragma unroll
    for (int i = 0; i < 8; ++i) v[i] = (short)f2bf(h1f[c8 + i]);
    *(bf16x8*)(smem + HT(0) + (c8 >> 5)*FRAGB + gr*ROWB + (c8 & 31)*2) = v;
  }
  {
    const float* op = obs + (T*16 + (tid >> 5))*512;
    f32x2 p0 = *(const f32x2*)(op), p1 = *(const f32x2*)(op + 2);
    xtile(0, p1[0] - p0[0], p1[1] - p0[1]);
  }
  __syncthreads();

  float hv0 = 0.f, hv1 = 0.f;
  long guard = 0;

  for (int t = 0; t < T_STEPS; ++t){
    const int cur = t & 1;
    const int rowA = lc;
    // ---- x-part MFMA (no h_t dependency): frags 2kh, 2kh+1 ----
    f32x4 acc0 = (f32x4){bias[0],bias[0],bias[0],bias[0]};
    f32x4 acc1 = (f32x4){bias[1],bias[1],bias[1],bias[1]};
    f32x4 acc2 = (f32x4){bias[2],bias[2],bias[2],bias[2]};
    f32x4 acc3 = (f32x4){bias[3],bias[3],bias[3],bias[3]};
    #pragma unroll
    for (int kfl = 0; kfl < 2; ++kfl){
      const char* pa = smem + XT(cur) + (kh*2 + kfl)*FRAGB + rowA*ROWB + lg*16;
      bf16x8 a = *(const bf16x8*)pa;
      acc0 = __builtin_amdgcn_mfma_f32_16x16x32_bf16(a, wf[0][kfl], acc0, 0, 0, 0);
      acc1 = __builtin_amdgcn_mfma_f32_16x16x32_bf16(a, wf[1][kfl], acc1, 0, 0, 0);
      acc2 = __builtin_amdgcn_mfma_f32_16x16x32_bf16(a, wf[2][kfl], acc2, 0, 0, 0);
      acc3 = __builtin_amdgcn_mfma_f32_16x16x32_bf16(a, wf[3][kfl], acc3, 0, 0, 0);
    }

    // ---- gather h_t (t>0): direct tagged gather with retry [R4 semantics] ----
    if (t > 0){
      const unsigned want = ((unsigned)t) << 16;
      const unsigned int* src = hbuf + cur*262144 + T*4096 + gr*256 + c8;
      u32x4 q0, q1;
      unsigned bad;
      do {
        if (fast){
          asm volatile("global_load_dwordx4 %0, %2, off sc0 nt\n\t"
                       "global_load_dwordx4 %1, %2, off offset:16 sc0 nt\n\t"
                       "s_waitcnt vmcnt(0)"
                       : "=&v"(q0), "=&v"(q1) : "v"(src) : "memory");
        } else {
          #pragma unroll
          for (int i = 0; i < 4; ++i){
            q0[i] = AG_LD(src + i); q1[i] = AG_LD(src + 4 + i);
          }
        }
        bad = 0;
        #pragma unroll
        for (int i = 0; i < 4; ++i){
          bad |= (q0[i] ^ want) & 0xffff0000u;
          bad |= (q1[i] ^ want) & 0xffff0000u;
        }
      } while (bad && ++guard < 2000000L);

      bf16x8 v;
      #pragma unroll
      for (int i = 0; i < 4; ++i){
        v[i]     = (short)(q0[i] & 0xffffu);
        v[4 + i] = (short)(q1[i] & 0xffffu);
      }
      *(bf16x8*)(smem + HT(cur) + (c8 >> 5)*FRAGB + gr*ROWB + (c8 & 31)*2) = v;
    }

    // ---- xtile(t+1) into the other buffer ----
    if (t < T_STEPS - 1){
      const float* op = obs + (T*16 + (tid >> 5))*512 + (t + 1)*2;
      f32x2 p0 = *(const f32x2*)(op), p1 = *(const f32x2*)(op + 2);
      xtile(cur ^ 1, p1[0] - p0[0], p1[1] - p0[1]);
    }
    __syncthreads();                               // barrier A

    // ---- h-part MFMA: frags 4kh..4kh+3 ----
    #pragma unroll
    for (int kfl = 2; kfl < 6; ++kfl){
      const char* pa = smem + HT(cur) + (kh*4 + kfl - 2)*FRAGB + rowA*ROWB + lg*16;
      bf16x8 a = *(const bf16x8*)pa;
      acc0 = __builtin_amdgcn_mfma_f32_16x16x32_bf16(a, wf[0][kfl], acc0, 0, 0, 0);
      acc1 = __builtin_amdgcn_mfma_f32_16x16x32_bf16(a, wf[1][kfl], acc1, 0, 0, 0);
      acc2 = __builtin_amdgcn_mfma_f32_16x16x32_bf16(a, wf[2][kfl], acc2, 0, 0, 0);
      ac3:;
      acc3 = __builtin_amdgcn_mfma_f32_16x16x32_bf16(a, wf[3][kfl], acc3, 0, 0, 0);
    }
    // ---- redbuf export (partner's rows) [R10 exact] ----
    {
      f32x2* rb = (f32x2*)(smem + RB_OFF);
      const int sl = kh ^ 1;
      const int base = ((hsub*2 + sl)*4)*64 + l;
      f32x2 e0, e1, e2, e3;
      if (kh == 0){
        e0 = (f32x2){acc0[2], acc0[3]}; e1 = (f32x2){acc1[2], acc1[3]};
        e2 = (f32x2){acc2[2], acc2[3]}; e3 = (f32x2){acc3[2], acc3[3]};
      } else {
        e0 = (f32x2){acc0[0], acc0[1]}; e1 = (f32x2){acc1[0], acc1[1]};
        e2 = (f32x2){acc2[0], acc2[1]}; e3 = (f32x2){acc3[0], acc3[1]};
      }
      rb[base] = e0; rb[base + 64] = e1; rb[base + 128] = e2; rb[base + 192] = e3;
    }
    __syncthreads();                               // barrier B
    // ---- K-reduce own half + LSTM elementwise [R10 exact] ----
    {
      f32x2* rb = (f32x2*)(smem + RB_OFF);
      const int base = ((hsub*2 + kh)*4)*64 + l;
      f32x2 r0 = rb[base], r1 = rb[base + 64], r2 = rb[base + 128], r3 = rb[base + 192];
      float gi0, gi1, gf0, gf1, gg0, gg1, go0, go1;
      if (kh == 0){
        gi0 = acc0[0] + r0[0]; gi1 = acc0[1] + r0[1];
        gf0 = acc1[0] + r1[0]; gf1 = acc1[1] + r1[1];
        gg0 = acc2[0] + r2[0]; gg1 = acc2[1] + r2[1];
        go0 = acc3[0] + r3[0]; go1 = acc3[1] + r3[1];
      } else {
        gi0 = acc0[2] + r0[0]; gi1 = acc0[3] + r0[1];
        gf0 = acc1[2] + r1[0]; gf1 = acc1[3] + r1[1];
        gg0 = acc2[2] + r2[0]; gg1 = acc2[3] + r2[1];
        go0 = acc3[2] + r3[0]; go1 = acc3[3] + r3[1];
      }
      cs0 = sigf(gf0)*cs0 + sigf(gi0)*tanh_(gg0);
      hv0 = sigf(go0)*tanh_(cs0);
      cs1 = sigf(gf1)*cs1 + sigf(gi1)*tanh_(gg1);
      hv1 = sigf(go1)*tanh_(cs1);
    }

    // ---- publish h_{t+1} (tagged) [R10 exact] ----
    if (t < T_STEPS - 1){
      const unsigned want2 = ((unsigned)(t + 1)) << 16;
      unsigned w0 = want2 | f2bf(hv0);
      unsigned w1 = want2 | f2bf(hv1);
      unsigned int* dst = hbuf + (cur ^ 1)*262144 + T*4096 + row0*256 + col;
      if (fast){
        asm volatile("global_store_dword %0, %1, off sc0\n\t"
                     "global_store_dword %0, %2, off offset:1024 sc0"
                     :: "v"(dst), "v"(w0), "v"(w1) : "memory");
      } else {
        AG_ST(dst, w0); AG_ST(dst + 256, w1);
      }
    }
    // no end-of-loop barrier: B_t orders iter-t reads vs iter-(t+1) writes (post A_{t+1})
  }

  // ---- done-rendezvous (degree 4) before epilogue overwrites hbuf [R10 exact] ----
  if (tid == 0) AG_ST(flags + (T*4 + q)*16 + 10, 1u);
  if (tid < 4){
    unsigned v; long g = 0;
    do { v = AG_LD(flags + (T*4 + tid)*16 + 10); } while (v == 0 && ++g < 10000000L);
  }
  __syncthreads();

  // ---- epilogue: final (h, c) f32 for this lane's 2 rows ----
  {
    const int r = T*16 + row0;
    out[r*256 + col]                = hv0;
    out[(r + 1)*256 + col]          = hv1;
    out[262144 + r*256 + col]       = cs0;
    out[262144 + (r + 1)*256 + col] = cs1;
  }
}

extern "C" void kernel_launch(void* const* d_in, const int* in_sizes, int n_in,
                              void* d_out, int out_size, void* d_ws, size_t ws_size,
                              hipStream_t stream) {
  (void)in_sizes; (void)n_in; (void)out_size; (void)ws_size;
  const float* obs  = (const float*)d_in[0];
  /* d_in[1] = pooled: unused */
  const float* Wemb = (const float*)d_in[2];
  const float* Bemb = (const float*)d_in[3];
  const float* Wih  = (const float*)d_in[4];
  const float* Whh  = (const float*)d_in[5];
  const float* bih  = (const float*)d_in[6];
  const float* bhh  = (const float*)d_in[7];
  float* out = (float*)d_out;
  unsigned int* flags = (unsigned int*)d_ws;        // 64KB: xcd/rendezvous words
  unsigned int* hbuf  = (unsigned int*)d_out;       // tagged exchange lives in d_out

  zero_ws<<<dim3(1056), dim3(512), 0, stream>>>(flags, hbuf);
  lstm_k<<<dim3(256), dim3(512), 0, stream>>>(obs, Wemb, Bemb, Wih, Whh, bih, bhh,
                                              out, flags, hbuf);
}

// Round 12
// 397.766 us; speedup vs baseline: 2.8159x; 1.1665x over previous
//
#include <hip/hip_runtime.h>
#include <stdint.h>

// LSTM_49357764165950 — MI355X (gfx950), round 12
// = R11 (464us: 256 CUs, 8 waves=2/SIMD, K-half redbuf, pipelined tagged exchange)
// + three surgical changes:
//  (1) EARLY-ISSUE GATHER: issue the 2 dwordx4 loads BEFORE xtile, s_waitcnt+tag-check
//      after ("+v" inout on the waitcnt asm pins the check after the wait, rule-#18).
//      xtile has no global ops (obs drained at loop top) -> first L2 RT overlaps xtile.
//  (2) v_cvt_pk_bf16_f32 (HW RTNE, == old manual RTNE) for xtile + publish converts.
//  (3) FRAGB 1296 -> 1312 (frag stride == 8 mod 32 banks): gather bf16x8 LDS writes
//      4-way -> 2-way (free). Same macro on writer and reader.
// Protocol/barriers/redbuf/XCD-check/2-slot chain: R11-verbatim.

typedef float  f32x4  __attribute__((ext_vector_type(4)));
typedef float  f32x2  __attribute__((ext_vector_type(2)));
typedef short  bf16x8 __attribute__((ext_vector_type(8)));
typedef unsigned int u32x4 __attribute__((ext_vector_type(4)));
typedef unsigned int u32x2 __attribute__((ext_vector_type(2)));

#define T_STEPS 255
#define ROWB    80                      // bytes per 32-col bf16 row (64B data + 16B pad)
#define FRAGB   1312                    // 16 rows * 80B + 32B pad (328 dw == 8 mod 32)
#define XT(b)   ((b)*4*FRAGB)           // x frags kf 0..3   (0, 5248)
#define HT(b)   (10496 + (b)*8*FRAGB)   // h frags 0..7      (10496, 20992; end 31488)
#define RB_OFF  31488                   // redbuf [8 slots][4 gates][64] f32x2 = 16KB
#define WM_OFF  47872                   // wm0p[160] wm1p[160] bemp[160] f32 (+xs scratch)
#define H1_OFF  49792                   // h1f[256] f32
#define C1_OFF  50816                   // c1f[256] f32
#define SMEM_SZ 52224

#define AG_ST(p, v) __hip_atomic_store((p), (v), __ATOMIC_RELAXED, __HIP_MEMORY_SCOPE_AGENT)
#define AG_LD(p)    __hip_atomic_load((p),        __ATOMIC_RELAXED, __HIP_MEMORY_SCOPE_AGENT)

__device__ __forceinline__ unsigned short f2bf(float f){
  union { float f; unsigned int u; } v; v.f = f;
  unsigned int u = v.u;
  return (unsigned short)((u + 0x7fffu + ((u >> 16) & 1u)) >> 16);   // RTNE
}
__device__ __forceinline__ float sigf(float x){
  float e = __builtin_amdgcn_exp2f(-1.4426950408889634f * x);
  return __builtin_amdgcn_rcpf(1.0f + e);
}
__device__ __forceinline__ float tanh_(float x){
  float e = __builtin_amdgcn_exp2f(-2.8853900817779268f * x);
  return (1.0f - e) * __builtin_amdgcn_rcpf(1.0f + e);
}

__global__ void zero_ws(unsigned int* flags, unsigned int* outw){
  const unsigned idx = blockIdx.x*512u + threadIdx.x;
  if (idx < 16384u)        AG_ST(flags + idx, 0u);
  else if (idx < 540672u)  AG_ST(outw + (idx - 16384u), 0u);
}

__global__ void __launch_bounds__(512, 2)
lstm_k(const float* __restrict__ obs,
       const float* __restrict__ Wemb, const float* __restrict__ Bemb,
       const float* __restrict__ Wih,  const float* __restrict__ Whh,
       const float* __restrict__ bih,  const float* __restrict__ bhh,
       float* out, unsigned int* flags, unsigned int* hbuf)   // hbuf aliases out
{
  __shared__ __align__(16) char smem[SMEM_SZ];
  const int tid  = threadIdx.x;
  const int l    = tid & 63;
  const int w    = tid >> 6;           // 0..7
  const int hsub = w & 3;              // 16-col group within the quarter
  const int kh   = w >> 2;             // K-half
  const int lc   = l & 15;
  const int lg   = l >> 4;
  const int T    = blockIdx.x & 63;    // batch tile (16 rows)
  const int q    = blockIdx.x >> 6;    // H-quarter 0..3; partners delta=64 (same XCD)

  // ---- XCD-affinity check, 2 rounds, degree 4 [R11 exact] ----
  unsigned xcc;
  asm volatile("s_getreg_b32 %0, hwreg(HW_REG_XCC_ID)" : "=s"(xcc));
  bool fast;
  {
    volatile unsigned* xs = (volatile unsigned*)(smem + WM_OFF);
    if (tid == 0) AG_ST(flags + (T*4 + q)*16 + 8, 1u + xcc);
    if (tid < 4){
      unsigned v; long g = 0;
      do { v = AG_LD(flags + (T*4 + tid)*16 + 8); } while (v == 0 && ++g < 10000000L);
      xs[tid] = v;
    }
    __syncthreads();
    unsigned ok = 1;
    #pragma unroll
    for (int j = 0; j < 4; ++j) ok &= (xs[j] == 1u + xcc) ? 1u : 0u;
    __syncthreads();
    if (tid == 0) AG_ST(flags + (T*4 + q)*16 + 9, ok ? 2u : 1u);
    if (tid < 4){
      unsigned v; long g = 0;
      do { v = AG_LD(flags + (T*4 + tid)*16 + 9); } while (v == 0 && ++g < 10000000L);
      xs[tid] = v;
    }
    __syncthreads();
    unsigned all2 = 1;
    #pragma unroll
    for (int j = 0; j < 4; ++j) all2 &= (xs[j] == 2u) ? 1u : 0u;
    fast = (all2 != 0);
    __syncthreads();                       // before WM area reuse
  }

  // ---- register-resident W fragments: 4 gates x (2 x-frags + 4 h-frags) [R11] ----
  bf16x8 wf[4][6];
  #pragma unroll
  for (int g = 0; g < 4; ++g){
    const int rowg = g*256 + q*64 + hsub*16 + lc;
    #pragma unroll
    for (int kfl = 0; kfl < 6; ++kfl){
      const float* src;
      if (kfl < 2){
        const int k0 = (kh*2 + kfl)*32 + lg*8;           // x: global K 0..127
        src = Wih + rowg*128 + k0;
      } else {
        const int k0 = (kh*4 + kfl - 2)*32 + lg*8;       // h: 0..255
        src = Whh + rowg*256 + k0;
      }
      f32x4 s0 = *(const f32x4*)(src);
      f32x4 s1 = *(const f32x4*)(src + 4);
      bf16x8 v;
      v[0]=(short)f2bf(s0[0]); v[1]=(short)f2bf(s0[1]);
      v[2]=(short)f2bf(s0[2]); v[3]=(short)f2bf(s0[3]);
      v[4]=(short)f2bf(s1[0]); v[5]=(short)f2bf(s1[1]);
      v[6]=(short)f2bf(s1[2]); v[7]=(short)f2bf(s1[3]);
      wf[g][kfl] = v;
    }
  }
  float bias[4];
  #pragma unroll
  for (int g = 0; g < 4; ++g){
    const int rowg = g*256 + q*64 + hsub*16 + lc;
    bias[g] = (kh == 0) ? (bih[rowg] + bhh[rowg]) : 0.f;
  }

  // ---- LDS tables (padded pi = f + (f>>4)*4) + tag step [R11 exact] ----
  float* wm0 = (float*)(smem + WM_OFF);        // [160]
  float* wm1 = wm0 + 160;
  float* bem = wm0 + 320;
  if (tid < 128){
    float a = 0.f, b = 0.f, c = 0.f;
    if (tid < 126){ a = 4.0f*Wemb[tid]; b = 4.0f*Wemb[126 + tid]; c = Bemb[tid]; }
    const int pi = tid + (tid >> 4)*4;
    wm0[pi] = a; wm1[pi] = b; bem[pi] = c;
  }
  float* h1f = (float*)(smem + H1_OFF);
  float* c1f = (float*)(smem + C1_OFF);
  if (tid < 256){
    const int j = tid;
    float gi  = Wih[(j      )*128 + 126] + bih[j      ] + bhh[j      ];
    float gg2 = Wih[(512 + j)*128 + 126] + bih[512 + j] + bhh[512 + j];
    float go  = Wih[(768 + j)*128 + 126] + bih[768 + j] + bhh[768 + j];
    float c1 = sigf(gi)*tanh_(gg2);
    h1f[j] = sigf(go)*tanh_(c1); c1f[j] = c1;
  }
  __syncthreads();

  // x-tile builder [R11 mapping; cvt_pk converts]
  auto xtile = [&](int buf, float vx, float vy){
    const int row = tid >> 5;
    const int cb  = (tid & 31) * 4;
    const int cp  = cb + (cb >> 4)*4;
    f32x4 wa = *(const f32x4*)(wm0 + cp);
    f32x4 wc = *(const f32x4*)(wm1 + cp);
    f32x4 ba = *(const f32x4*)(bem + cp);
    float e0 = fmaxf(vx*wa[0] + vy*wc[0] + ba[0], 0.f);
    float e1 = fmaxf(vx*wa[1] + vy*wc[1] + ba[1], 0.f);
    float e2 = fmaxf(vx*wa[2] + vy*wc[2] + ba[2], 0.f);
    float e3 = fmaxf(vx*wa[3] + vy*wc[3] + ba[3], 0.f);
    unsigned lo, hi;
    asm("v_cvt_pk_bf16_f32 %0, %1, %2" : "=v"(lo) : "v"(e0), "v"(e1));
    asm("v_cvt_pk_bf16_f32 %0, %1, %2" : "=v"(hi) : "v"(e2), "v"(e3));
    *(u32x2*)(smem + XT(buf) + (cb >> 5)*FRAGB + row*ROWB + (cb & 31)*2) = (u32x2){lo, hi};
  };

  // gather mapping [R11 exact]
  const int gr = tid >> 5;
  const int c8 = (tid & 31) * 8;

  // c-state (2 rows/lane) + h_tile[0] + x_tile[0]
  const int col  = q*64 + hsub*16 + lc;
  const int row0 = lg*4 + 2*kh;
  float cs0, cs1;
  { float cv = c1f[col]; cs0 = cv; cs1 = cv; }
  {
    bf16x8 v;
    #pragma unroll
    for (int i = 0; i < 8; ++i) v[i] = (short)f2bf(h1f[c8 + i]);
    *(bf16x8*)(smem + HT(0) + (c8 >> 5)*FRAGB + gr*ROWB + (c8 & 31)*2) = v;
  }
  {
    const float* op = obs + (T*16 + (tid >> 5))*512;
    f32x2 p0 = *(const f32x2*)(op), p1 = *(const f32x2*)(op + 2);
    xtile(0, p1[0] - p0[0], p1[1] - p0[1]);
  }
  __syncthreads();

  float hv0 = 0.f, hv1 = 0.f;
  long guard = 0;

  for (int t = 0; t < T_STEPS; ++t){
    const int cur = t & 1;
    const int rowA = lc;
    // obs prefetch + subtraction at top: drains obs loads BEFORE gather issue,
    // so no global op (hence no implicit vmcnt wait) sits between issue and check.
    float vx = 0.f, vy = 0.f;
    if (t < T_STEPS - 1){
      const float* op = obs + (T*16 + (tid >> 5))*512 + (t + 1)*2;
      f32x2 p0 = *(const f32x2*)(op), p1 = *(const f32x2*)(op + 2);
      vx = p1[0] - p0[0]; vy = p1[1] - p0[1];
    }
    // ---- x-part MFMA (no h_t dependency): frags 2kh, 2kh+1 [R11] ----
    f32x4 acc0 = (f32x4){bias[0],bias[0],bias[0],bias[0]};
    f32x4 acc1 = (f32x4){bias[1],bias[1],bias[1],bias[1]};
    f32x4 acc2 = (f32x4){bias[2],bias[2],bias[2],bias[2]};
    f32x4 acc3 = (f32x4){bias[3],bias[3],bias[3],bias[3]};
    #pragma unroll
    for (int kfl = 0; kfl < 2; ++kfl){
      const char* pa = smem + XT(cur) + (kh*2 + kfl)*FRAGB + rowA*ROWB + lg*16;
      bf16x8 a = *(const bf16x8*)pa;
      acc0 = __builtin_amdgcn_mfma_f32_16x16x32_bf16(a, wf[0][kfl], acc0, 0, 0, 0);
      acc1 = __builtin_amdgcn_mfma_f32_16x16x32_bf16(a, wf[1][kfl], acc1, 0, 0, 0);
      acc2 = __builtin_amdgcn_mfma_f32_16x16x32_bf16(a, wf[2][kfl], acc2, 0, 0, 0);
      acc3 = __builtin_amdgcn_mfma_f32_16x16x32_bf16(a, wf[3][kfl], acc3, 0, 0, 0);
    }

    // ---- gather h_t: EARLY-ISSUE (fast path), validate after xtile ----
    const unsigned int* src = hbuf + cur*262144 + T*4096 + gr*256 + c8;
    u32x4 q0, q1;
    const bool do_gather = (t > 0);
    if (do_gather && fast){
      asm volatile("global_load_dwordx4 %0, %2, off sc0 nt\n\t"
                   "global_load_dwordx4 %1, %2, off offset:16 sc0 nt"
                   : "=&v"(q0), "=&v"(q1) : "v"(src) : "memory");
    }

    // ---- xtile(t+1) into the other buffer (pure LDS/VALU) [R11] ----
    if (t < T_STEPS - 1) xtile(cur ^ 1, vx, vy);

    if (do_gather){
      const unsigned want = ((unsigned)t) << 16;
      unsigned bad;
      if (fast){
        // the "+v" inouts pin the tag-check AFTER the wait (rule #18)
        asm volatile("s_waitcnt vmcnt(0)" : "+v"(q0), "+v"(q1) :: "memory");
        bad = 0;
        #pragma unroll
        for (int i = 0; i < 4; ++i){
          bad |= (q0[i] ^ want) & 0xffff0000u;
          bad |= (q1[i] ^ want) & 0xffff0000u;
        }
        while (bad && ++guard < 2000000L){
          asm volatile("global_load_dwordx4 %0, %2, off sc0 nt\n\t"
                       "global_load_dwordx4 %1, %2, off offset:16 sc0 nt\n\t"
                       "s_waitcnt vmcnt(0)"
                       : "=&v"(q0), "=&v"(q1) : "v"(src) : "memory");
          bad = 0;
          #pragma unroll
          for (int i = 0; i < 4; ++i){
            bad |= (q0[i] ^ want) & 0xffff0000u;
            bad |= (q1[i] ^ want) & 0xffff0000u;
          }
        }
      } else {
        do {
          #pragma unroll
          for (int i = 0; i < 4; ++i){
            q0[i] = AG_LD(src + i); q1[i] = AG_LD(src + 4 + i);
          }
          bad = 0;
          #pragma unroll
          for (int i = 0; i < 4; ++i){
            bad |= (q0[i] ^ want) & 0xffff0000u;
            bad |= (q1[i] ^ want) & 0xffff0000u;
          }
        } while (bad && ++guard < 2000000L);
      }
      bf16x8 v;
      #pragma unroll
      for (int i = 0; i < 4; ++i){
        v[i]     = (short)(q0[i] & 0xffffu);
        v[4 + i] = (short)(q1[i] & 0xffffu);
      }
      *(bf16x8*)(smem + HT(cur) + (c8 >> 5)*FRAGB + gr*ROWB + (c8 & 31)*2) = v;
    }
    __syncthreads();                               // barrier A

    // ---- h-part MFMA: frags 4kh..4kh+3 [R11] ----
    #pragma unroll
    for (int kfl = 2; kfl < 6; ++kfl){
      const char* pa = smem + HT(cur) + (kh*4 + kfl - 2)*FRAGB + rowA*ROWB + lg*16;
      bf16x8 a = *(const bf16x8*)pa;
      acc0 = __builtin_amdgcn_mfma_f32_16x16x32_bf16(a, wf[0][kfl], acc0, 0, 0, 0);
      acc1 = __builtin_amdgcn_mfma_f32_16x16x32_bf16(a, wf[1][kfl], acc1, 0, 0, 0);
      acc2 = __builtin_amdgcn_mfma_f32_16x16x32_bf16(a, wf[2][kfl], acc2, 0, 0, 0);
      acc3 = __builtin_amdgcn_mfma_f32_16x16x32_bf16(a, wf[3][kfl], acc3, 0, 0, 0);
    }
    // ---- redbuf export (partner's rows) [R11 exact] ----
    {
      f32x2* rb = (f32x2*)(smem + RB_OFF);
      const int sl = kh ^ 1;
      const int base = ((hsub*2 + sl)*4)*64 + l;
      f32x2 e0, e1, e2, e3;
      if (kh == 0){
        e0 = (f32x2){acc0[2], acc0[3]}; e1 = (f32x2){acc1[2], acc1[3]};
        e2 = (f32x2){acc2[2], acc2[3]}; e3 = (f32x2){acc3[2], acc3[3]};
      } else {
        e0 = (f32x2){acc0[0], acc0[1]}; e1 = (f32x2){acc1[0], acc1[1]};
        e2 = (f32x2){acc2[0], acc2[1]}; e3 = (f32x2){acc3[0], acc3[1]};
      }
      rb[base] = e0; rb[base + 64] = e1; rb[base + 128] = e2; rb[base + 192] = e3;
    }
    __syncthreads();                               // barrier B
    // ---- K-reduce own half + LSTM elementwise [R11 exact] ----
    {
      f32x2* rb = (f32x2*)(smem + RB_OFF);
      const int base = ((hsub*2 + kh)*4)*64 + l;
      f32x2 r0 = rb[base], r1 = rb[base + 64], r2 = rb[base + 128], r3 = rb[base + 192];
      float gi0, gi1, gf0, gf1, gg0, gg1, go0, go1;
      if (kh == 0){
        gi0 = acc0[0] + r0[0]; gi1 = acc0[1] + r0[1];
        gf0 = acc1[0] + r1[0]; gf1 = acc1[1] + r1[1];
        gg0 = acc2[0] + r2[0]; gg1 = acc2[1] + r2[1];
        go0 = acc3[0] + r3[0]; go1 = acc3[1] + r3[1];
      } else {
        gi0 = acc0[2] + r0[0]; gi1 = acc0[3] + r0[1];
        gf0 = acc1[2] + r1[0]; gf1 = acc1[3] + r1[1];
        gg0 = acc2[2] + r2[0]; gg1 = acc2[3] + r2[1];
        go0 = acc3[2] + r3[0]; go1 = acc3[3] + r3[1];
      }
      cs0 = sigf(gf0)*cs0 + sigf(gi0)*tanh_(gg0);
      hv0 = sigf(go0)*tanh_(cs0);
      cs1 = sigf(gf1)*cs1 + sigf(gi1)*tanh_(gg1);
      hv1 = sigf(go1)*tanh_(cs1);
    }

    // ---- publish h_{t+1} (tagged; cvt_pk pack) ----
    if (t < T_STEPS - 1){
      const unsigned want2 = ((unsigned)(t + 1)) << 16;
      unsigned pk;
      asm("v_cvt_pk_bf16_f32 %0, %1, %2" : "=v"(pk) : "v"(hv0), "v"(hv1));
      unsigned w0 = want2 | (pk & 0xffffu);
      unsigned w1 = want2 | (pk >> 16);
      unsigned int* dst = hbuf + (cur ^ 1)*262144 + T*4096 + row0*256 + col;
      if (fast){
        asm volatile("global_store_dword %0, %1, off sc0\n\t"
                     "global_store_dword %0, %2, off offset:1024 sc0"
                     :: "v"(dst), "v"(w0), "v"(w1) : "memory");
      } else {
        AG_ST(dst, w0); AG_ST(dst + 256, w1);
      }
    }
    // no end-of-loop barrier [R11]: B_t orders iter-t reads vs iter-(t+1) writes
  }

  // ---- done-rendezvous (degree 4) before epilogue overwrites hbuf [R11 exact] ----
  if (tid == 0) AG_ST(flags + (T*4 + q)*16 + 10, 1u);
  if (tid < 4){
    unsigned v; long g = 0;
    do { v = AG_LD(flags + (T*4 + tid)*16 + 10); } while (v == 0 && ++g < 10000000L);
  }
  __syncthreads();

  // ---- epilogue: final (h, c) f32 for this lane's 2 rows [R11 exact] ----
  {
    const int r = T*16 + row0;
    out[r*256 + col]                = hv0;
    out[(r + 1)*256 + col]          = hv1;
    out[262144 + r*256 + col]       = cs0;
    out[262144 + (r + 1)*256 + col] = cs1;
  }
}

extern "C" void kernel_launch(void* const* d_in, const int* in_sizes, int n_in,
                              void* d_out, int out_size, void* d_ws, size_t ws_size,
                              hipStream_t stream) {
  (void)in_sizes; (void)n_in; (void)out_size; (void)ws_size;
  const float* obs  = (const float*)d_in[0];
  /* d_in[1] = pooled: unused */
  const float* Wemb = (const float*)d_in[2];
  const float* Bemb = (const float*)d_in[3];
  const float* Wih  = (const float*)d_in[4];
  const float* Whh  = (const float*)d_in[5];
  const float* bih  = (const float*)d_in[6];
  const float* bhh  = (const float*)d_in[7];
  float* out = (float*)d_out;
  unsigned int* flags = (unsigned int*)d_ws;        // 64KB: xcd/rendezvous words
  unsigned int* hbuf  = (unsigned int*)d_out;       // tagged exchange lives in d_out

  zero_ws<<<dim3(1056), dim3(512), 0, stream>>>(flags, hbuf);
  lstm_k<<<dim3(256), dim3(512), 0, stream>>>(obs, Wemb, Bemb, Wih, Whh, bih, bhh,
                                              out, flags, hbuf);
}

// Round 13
// 385.829 us; speedup vs baseline: 2.9030x; 1.0309x over previous
//
#include <hip/hip_runtime.h>
#include <stdint.h>

// LSTM_49357764165950 — MI355X (gfx950), round 13
// = R12 (398us) protocol-verbatim, with a leaner step:
//  (1) t-loop UNROLLED x2 (peel t=0, 126 pairs, 2-step tail): CUR is a compile-time
//      literal -> all LDS addrs fold to ds-offset immediates, hbuf ptrs hoisted (x2).
//  (2) CARRIED obs prefetch: obs(t+2) issued just BEFORE barrier A (whose vmcnt(0)
//      drain absorbs the L3 latency); consumed next iteration -> subs wait on nothing.
//      (R12 exposed ~200-300cy of obs latency at loop top every step.)
//  (3) gather issued at the very top of the step (before x-MFMA) -> ~80cy more overlap.
//  (4) VALU trims: pairwise unpack (lo|hi<<16, 8 ops), accumulate tag-check (16 ops),
//      hoisted redbuf/gather/xtile bases.
// Protocol/barriers/redbuf/XCD-check/2-slot chain/tags: R12-verbatim.

typedef float  f32x4  __attribute__((ext_vector_type(4)));
typedef float  f32x2  __attribute__((ext_vector_type(2)));
typedef short  bf16x8 __attribute__((ext_vector_type(8)));
typedef unsigned int u32x4 __attribute__((ext_vector_type(4)));
typedef unsigned int u32x2 __attribute__((ext_vector_type(2)));

#define T_STEPS 255
#define ROWB    80
#define FRAGB   1312
#define XTO(b)  ((b)*4*FRAGB)            // 0, 5248
#define HTO(b)  (10496 + (b)*8*FRAGB)    // 10496, 20992 (end 31488)
#define RB_OFF  31488
#define WM_OFF  47872
#define H1_OFF  49792
#define C1_OFF  50816
#define SMEM_SZ 52224

#define AG_ST(p, v) __hip_atomic_store((p), (v), __ATOMIC_RELAXED, __HIP_MEMORY_SCOPE_AGENT)
#define AG_LD(p)    __hip_atomic_load((p),        __ATOMIC_RELAXED, __HIP_MEMORY_SCOPE_AGENT)

__device__ __forceinline__ unsigned short f2bf(float f){
  union { float f; unsigned int u; } v; v.f = f;
  unsigned int u = v.u;
  return (unsigned short)((u + 0x7fffu + ((u >> 16) & 1u)) >> 16);   // RTNE
}
__device__ __forceinline__ float sigf(float x){
  float e = __builtin_amdgcn_exp2f(-1.4426950408889634f * x);
  return __builtin_amdgcn_rcpf(1.0f + e);
}
__device__ __forceinline__ float tanh_(float x){
  float e = __builtin_amdgcn_exp2f(-2.8853900817779268f * x);
  return (1.0f - e) * __builtin_amdgcn_rcpf(1.0f + e);
}

__global__ void zero_ws(unsigned int* flags, unsigned int* outw){
  const unsigned idx = blockIdx.x*512u + threadIdx.x;
  if (idx < 16384u)        AG_ST(flags + idx, 0u);
  else if (idx < 540672u)  AG_ST(outw + (idx - 16384u), 0u);
}

__global__ void __launch_bounds__(512, 2)
lstm_k(const float* __restrict__ obs,
       const float* __restrict__ Wemb, const float* __restrict__ Bemb,
       const float* __restrict__ Wih,  const float* __restrict__ Whh,
       const float* __restrict__ bih,  const float* __restrict__ bhh,
       float* out, unsigned int* flags, unsigned int* hbuf)   // hbuf aliases out
{
  __shared__ __align__(16) char smem[SMEM_SZ];
  const int tid  = threadIdx.x;
  const int l    = tid & 63;
  const int w    = tid >> 6;
  const int hsub = w & 3;
  const int kh   = w >> 2;
  const int lc   = l & 15;
  const int lg   = l >> 4;
  const int T    = blockIdx.x & 63;
  const int q    = blockIdx.x >> 6;

  // ---- XCD-affinity check, 2 rounds, degree 4 [R12 exact] ----
  unsigned xcc;
  asm volatile("s_getreg_b32 %0, hwreg(HW_REG_XCC_ID)" : "=s"(xcc));
  bool fast;
  {
    volatile unsigned* xs = (volatile unsigned*)(smem + WM_OFF);
    if (tid == 0) AG_ST(flags + (T*4 + q)*16 + 8, 1u + xcc);
    if (tid < 4){
      unsigned v; long g = 0;
      do { v = AG_LD(flags + (T*4 + tid)*16 + 8); } while (v == 0 && ++g < 10000000L);
      xs[tid] = v;
    }
    __syncthreads();
    unsigned ok = 1;
    #pragma unroll
    for (int j = 0; j < 4; ++j) ok &= (xs[j] == 1u + xcc) ? 1u : 0u;
    __syncthreads();
    if (tid == 0) AG_ST(flags + (T*4 + q)*16 + 9, ok ? 2u : 1u);
    if (tid < 4){
      unsigned v; long g = 0;
      do { v = AG_LD(flags + (T*4 + tid)*16 + 9); } while (v == 0 && ++g < 10000000L);
      xs[tid] = v;
    }
    __syncthreads();
    unsigned all2 = 1;
    #pragma unroll
    for (int j = 0; j < 4; ++j) all2 &= (xs[j] == 2u) ? 1u : 0u;
    fast = (all2 != 0);
    __syncthreads();
  }

  // ---- register-resident W fragments [R12 exact] ----
  bf16x8 wf[4][6];
  #pragma unroll
  for (int g = 0; g < 4; ++g){
    const int rowg = g*256 + q*64 + hsub*16 + lc;
    #pragma unroll
    for (int kfl = 0; kfl < 6; ++kfl){
      const float* src;
      if (kfl < 2){
        const int k0 = (kh*2 + kfl)*32 + lg*8;
        src = Wih + rowg*128 + k0;
      } else {
        const int k0 = (kh*4 + kfl - 2)*32 + lg*8;
        src = Whh + rowg*256 + k0;
      }
      f32x4 s0 = *(const f32x4*)(src);
      f32x4 s1 = *(const f32x4*)(src + 4);
      bf16x8 v;
      v[0]=(short)f2bf(s0[0]); v[1]=(short)f2bf(s0[1]);
      v[2]=(short)f2bf(s0[2]); v[3]=(short)f2bf(s0[3]);
      v[4]=(short)f2bf(s1[0]); v[5]=(short)f2bf(s1[1]);
      v[6]=(short)f2bf(s1[2]); v[7]=(short)f2bf(s1[3]);
      wf[g][kfl] = v;
    }
  }
  float bias[4];
  #pragma unroll
  for (int g = 0; g < 4; ++g){
    const int rowg = g*256 + q*64 + hsub*16 + lc;
    bias[g] = (kh == 0) ? (bih[rowg] + bhh[rowg]) : 0.f;
  }

  // ---- LDS tables (padded) + tag step [R12 exact] ----
  float* wm0 = (float*)(smem + WM_OFF);
  float* wm1 = wm0 + 160;
  float* bem = wm0 + 320;
  if (tid < 128){
    float a = 0.f, b = 0.f, c = 0.f;
    if (tid < 126){ a = 4.0f*Wemb[tid]; b = 4.0f*Wemb[126 + tid]; c = Bemb[tid]; }
    const int pi = tid + (tid >> 4)*4;
    wm0[pi] = a; wm1[pi] = b; bem[pi] = c;
  }
  float* h1f = (float*)(smem + H1_OFF);
  float* c1f = (float*)(smem + C1_OFF);
  if (tid < 256){
    const int j = tid;
    float gi  = Wih[(j      )*128 + 126] + bih[j      ] + bhh[j      ];
    float gg2 = Wih[(512 + j)*128 + 126] + bih[512 + j] + bhh[512 + j];
    float go  = Wih[(768 + j)*128 + 126] + bih[768 + j] + bhh[768 + j];
    float c1 = sigf(gi)*tanh_(gg2);
    h1f[j] = sigf(go)*tanh_(c1); c1f[j] = c1;
  }
  __syncthreads();

  // ---- hoisted bases ----
  const int gr = tid >> 5;
  const int c8 = (tid & 31) * 8;
  const int col  = q*64 + hsub*16 + lc;
  const int row0 = lg*4 + 2*kh;
  const float* obs_base = obs + (T*16 + gr)*512;
  char* const xwb   = smem + (((tid & 31)*4) >> 5)*FRAGB + gr*ROWB + (((tid & 31)*4) & 31)*2; // xtile write
  const int  xcp    = ((tid & 31)*4) + (((tid & 31)*4) >> 4)*4;                               // padded table idx
  char* const gwb   = smem + (c8 >> 5)*FRAGB + gr*ROWB + (c8 & 31)*2;    // gather LDS write
  const char* const abx = smem + kh*2*FRAGB + lc*ROWB + lg*16;           // x-MFMA read base
  const char* const abh = smem + kh*4*FRAGB + lc*ROWB + lg*16;           // h-MFMA read base
  f32x2* const rb = (f32x2*)(smem + RB_OFF);
  const int rb_exp = (hsub*2 + (kh ^ 1))*256 + l;
  const int rb_red = (hsub*2 + kh)*256 + l;
  unsigned int* const dstP[2] = { hbuf + 262144 + T*4096 + row0*256 + col,   // CUR=0 -> slot1
                                  hbuf +          T*4096 + row0*256 + col }; // CUR=1 -> slot0
  const unsigned int* const srcP[2] = { hbuf +          T*4096 + gr*256 + c8,   // CUR=0 reads slot0
                                        hbuf + 262144 + T*4096 + gr*256 + c8 }; // CUR=1 reads slot1

  auto xtile = [&](int buf, float vx, float vy){
    f32x4 wa = *(const f32x4*)(wm0 + xcp);
    f32x4 wc = *(const f32x4*)(wm1 + xcp);
    f32x4 ba = *(const f32x4*)(bem + xcp);
    float e0 = fmaxf(vx*wa[0] + vy*wc[0] + ba[0], 0.f);
    float e1 = fmaxf(vx*wa[1] + vy*wc[1] + ba[1], 0.f);
    float e2 = fmaxf(vx*wa[2] + vy*wc[2] + ba[2], 0.f);
    float e3 = fmaxf(vx*wa[3] + vy*wc[3] + ba[3], 0.f);
    unsigned lo, hi;
    asm("v_cvt_pk_bf16_f32 %0, %1, %2" : "=v"(lo) : "v"(e0), "v"(e1));
    asm("v_cvt_pk_bf16_f32 %0, %1, %2" : "=v"(hi) : "v"(e2), "v"(e3));
    *(u32x2*)(xwb + XTO(0) + buf*XTO(1)) = (u32x2){lo, hi};
  };

  // c-state + h_tile[0] + x_tile[0]
  float cs0, cs1;
  { float cv = c1f[col]; cs0 = cv; cs1 = cv; }
  {
    bf16x8 v;
    #pragma unroll
    for (int i = 0; i < 8; ++i) v[i] = (short)f2bf(h1f[c8 + i]);
    *(bf16x8*)(gwb + HTO(0)) = v;
  }
  {
    f32x2 p0 = *(const f32x2*)(obs_base), p1 = *(const f32x2*)(obs_base + 2);
    xtile(0, p1[0] - p0[0], p1[1] - p0[1]);
  }
  // carried obs prefetch for iteration t=0's xtile(1): obs(1), obs(2)
  f32x2 pc0 = *(const f32x2*)(obs_base + 2);
  f32x2 pc1 = *(const f32x2*)(obs_base + 4);
  __syncthreads();

  float hv0 = 0.f, hv1 = 0.f;
  long guard = 0;

#define STEP(CUR, tv, DO_GATHER)                                                     \
  {                                                                                  \
    u32x4 q0, q1;                                                                    \
    if (DO_GATHER && fast){                                                          \
      asm volatile("global_load_dwordx4 %0, %2, off sc0 nt\n\t"                      \
                   "global_load_dwordx4 %1, %2, off offset:16 sc0 nt"                \
                   : "=&v"(q0), "=&v"(q1) : "v"(srcP[CUR]) : "memory");              \
    }                                                                                \
    f32x4 acc0 = (f32x4){bias[0],bias[0],bias[0],bias[0]};                           \
    f32x4 acc1 = (f32x4){bias[1],bias[1],bias[1],bias[1]};                           \
    f32x4 acc2 = (f32x4){bias[2],bias[2],bias[2],bias[2]};                           \
    f32x4 acc3 = (f32x4){bias[3],bias[3],bias[3],bias[3]};                           \
    _Pragma("unroll")                                                                \
    for (int kfl = 0; kfl < 2; ++kfl){                                               \
      bf16x8 a = *(const bf16x8*)(abx + XTO(CUR) + kfl*FRAGB);                       \
      acc0 = __builtin_amdgcn_mfma_f32_16x16x32_bf16(a, wf[0][kfl], acc0, 0, 0, 0);  \
      acc1 = __builtin_amdgcn_mfma_f32_16x16x32_bf16(a, wf[1][kfl], acc1, 0, 0, 0);  \
      acc2 = __builtin_amdgcn_mfma_f32_16x16x32_bf16(a, wf[2][kfl], acc2, 0, 0, 0);  \
      acc3 = __builtin_amdgcn_mfma_f32_16x16x32_bf16(a, wf[3][kfl], acc3, 0, 0, 0);  \
    }                                                                                \
    if ((tv) < T_STEPS - 1){                                                         \
      float vx = pc1[0] - pc0[0], vy = pc1[1] - pc0[1];                              \
      xtile((CUR) ^ 1, vx, vy);                                                      \
    }                                                                                \
    if (DO_GATHER){                                                                  \
      const unsigned want = ((unsigned)(tv)) << 16;                                  \
      unsigned bad;                                                                  \
      if (fast){                                                                     \
        asm volatile("s_waitcnt vmcnt(0)" : "+v"(q0), "+v"(q1) :: "memory");         \
        unsigned x = (q0[0]^want)|(q0[1]^want)|(q0[2]^want)|(q0[3]^want)             \
                   | (q1[0]^want)|(q1[1]^want)|(q1[2]^want)|(q1[3]^want);            \
        bad = x & 0xffff0000u;                                                       \
        while (bad && ++guard < 2000000L){                                           \
          asm volatile("global_load_dwordx4 %0, %2, off sc0 nt\n\t"                  \
                       "global_load_dwordx4 %1, %2, off offset:16 sc0 nt\n\t"        \
                       "s_waitcnt vmcnt(0)"                                          \
                       : "=&v"(q0), "=&v"(q1) : "v"(srcP[CUR]) : "memory");          \
          x = (q0[0]^want)|(q0[1]^want)|(q0[2]^want)|(q0[3]^want)                    \
            | (q1[0]^want)|(q1[1]^want)|(q1[2]^want)|(q1[3]^want);                   \
          bad = x & 0xffff0000u;                                                     \
        }                                                                            \
      } else {                                                                       \
        do {                                                                         \
          _Pragma("unroll")                                                          \
          for (int i = 0; i < 4; ++i){                                               \
            q0[i] = AG_LD(srcP[CUR] + i); q1[i] = AG_LD(srcP[CUR] + 4 + i);          \
          }                                                                          \
          unsigned x = (q0[0]^want)|(q0[1]^want)|(q0[2]^want)|(q0[3]^want)           \
                     | (q1[0]^want)|(q1[1]^want)|(q1[2]^want)|(q1[3]^want);          \
          bad = x & 0xffff0000u;                                                     \
        } while (bad && ++guard < 2000000L);                                         \
      }                                                                              \
      unsigned d0 = (q0[0] & 0xffffu) | (q0[1] << 16);                               \
      unsigned d1 = (q0[2] & 0xffffu) | (q0[3] << 16);                               \
      unsigned d2 = (q1[0] & 0xffffu) | (q1[1] << 16);                               \
      unsigned d3 = (q1[2] & 0xffffu) | (q1[3] << 16);                               \
      *(u32x4*)(gwb + HTO(CUR)) = (u32x4){d0, d1, d2, d3};                           \
    }                                                                                \
    if ((tv) < T_STEPS - 2){                                                         \
      pc0 = *(const f32x2*)(obs_base + ((tv) + 2)*2);                                \
      pc1 = *(const f32x2*)(obs_base + ((tv) + 2)*2 + 2);                            \
    }                                                                                \
    __syncthreads();  /* barrier A: drains obs prefetch too */                       \
    _Pragma("unroll")                                                                \
    for (int kfl = 2; kfl < 6; ++kfl){                                               \
      bf16x8 a = *(const bf16x8*)(abh + HTO(CUR) + (kfl - 2)*FRAGB);                 \
      acc0 = __builtin_amdgcn_mfma_f32_16x16x32_bf16(a, wf[0][kfl], acc0, 0, 0, 0);  \
      acc1 = __builtin_amdgcn_mfma_f32_16x16x32_bf16(a, wf[1][kfl], acc1, 0, 0, 0);  \
      acc2 = __builtin_amdgcn_mfma_f32_16x16x32_bf16(a, wf[2][kfl], acc2, 0, 0, 0);  \
      acc3 = __builtin_amdgcn_mfma_f32_16x16x32_bf16(a, wf[3][kfl], acc3, 0, 0, 0);  \
    }                                                                                \
    {                                                                                \
      f32x2 e0, e1, e2, e3;                                                          \
      if (kh == 0){                                                                  \
        e0 = (f32x2){acc0[2], acc0[3]}; e1 = (f32x2){acc1[2], acc1[3]};              \
        e2 = (f32x2){acc2[2], acc2[3]}; e3 = (f32x2){acc3[2], acc3[3]};              \
      } else {                                                                       \
        e0 = (f32x2){acc0[0], acc0[1]}; e1 = (f32x2){acc1[0], acc1[1]};              \
        e2 = (f32x2){acc2[0], acc2[1]}; e3 = (f32x2){acc3[0], acc3[1]};              \
      }                                                                              \
      rb[rb_exp] = e0; rb[rb_exp + 64] = e1;                                         \
      rb[rb_exp + 128] = e2; rb[rb_exp + 192] = e3;                                  \
    }                                                                                \
    __syncthreads();  /* barrier B */                                                \
    {                                                                                \
      f32x2 r0 = rb[rb_red], r1 = rb[rb_red + 64];                                   \
      f32x2 r2 = rb[rb_red + 128], r3 = rb[rb_red + 192];                            \
      float gi0, gi1, gf0, gf1, gg0, gg1, go0, go1;                                  \
      if (kh == 0){                                                                  \
        gi0 = acc0[0] + r0[0]; gi1 = acc0[1] + r0[1];                                \
        gf0 = acc1[0] + r1[0]; gf1 = acc1[1] + r1[1];                                \
        gg0 = acc2[0] + r2[0]; gg1 = acc2[1] + r2[1];                                \
        go0 = acc3[0] + r3[0]; go1 = acc3[1] + r3[1];                                \
      } else {                                                                       \
        gi0 = acc0[2] + r0[0]; gi1 = acc0[3] + r0[1];                                \
        gf0 = acc1[2] + r1[0]; gf1 = acc1[3] + r1[1];                                \
        gg0 = acc2[2] + r2[0]; gg1 = acc2[3] + r2[1];                                \
        go0 = acc3[2] + r3[0]; go1 = acc3[3] + r3[1];                                \
      }                                                                              \
      cs0 = sigf(gf0)*cs0 + sigf(gi0)*tanh_(gg0);                                    \
      hv0 = sigf(go0)*tanh_(cs0);                                                    \
      cs1 = sigf(gf1)*cs1 + sigf(gi1)*tanh_(gg1);                                    \
      hv1 = sigf(go1)*tanh_(cs1);                                                    \
    }                                                                                \
    if ((tv) < T_STEPS - 1){                                                         \
      const unsigned want2 = ((unsigned)((tv) + 1)) << 16;                           \
      unsigned pk;                                                                   \
      asm("v_cvt_pk_bf16_f32 %0, %1, %2" : "=v"(pk) : "v"(hv0), "v"(hv1));           \
      unsigned w0 = want2 | (pk & 0xffffu);                                          \
      unsigned w1 = want2 | (pk >> 16);                                              \
      if (fast){                                                                     \
        asm volatile("global_store_dword %0, %1, off sc0\n\t"                        \
                     "global_store_dword %0, %2, off offset:1024 sc0"                \
                     :: "v"(dstP[CUR]), "v"(w0), "v"(w1) : "memory");                \
      } else {                                                                       \
        AG_ST(dstP[CUR], w0); AG_ST(dstP[CUR] + 256, w1);                            \
      }                                                                              \
    }                                                                                \
  }

  STEP(0, 0, 0)                                  // peel t=0 (no gather)
  for (int t = 1; t < 253; t += 2){
    STEP(1, t, 1)
    STEP(0, t + 1, 1)
  }
  STEP(1, 253, 1)
  STEP(0, 254, 1)
#undef STEP

  // ---- done-rendezvous (degree 4) before epilogue overwrites hbuf [R12 exact] ----
  if (tid == 0) AG_ST(flags + (T*4 + q)*16 + 10, 1u);
  if (tid < 4){
    unsigned v; long g = 0;
    do { v = AG_LD(flags + (T*4 + tid)*16 + 10); } while (v == 0 && ++g < 10000000L);
  }
  __syncthreads();

  // ---- epilogue [R12 exact] ----
  {
    const int r = T*16 + row0;
    out[r*256 + col]                = hv0;
    out[(r + 1)*256 + col]          = hv1;
    out[262144 + r*256 + col]       = cs0;
    out[262144 + (r + 1)*256 + col] = cs1;
  }
}

extern "C" void kernel_launch(void* const* d_in, const int* in_sizes, int n_in,
                              void* d_out, int out_size, void* d_ws, size_t ws_size,
                              hipStream_t stream) {
  (void)in_sizes; (void)n_in; (void)out_size; (void)ws_size;
  const float* obs  = (const float*)d_in[0];
  /* d_in[1] = pooled: unused */
  const float* Wemb = (const float*)d_in[2];
  const float* Bemb = (const float*)d_in[3];
  const float* Wih  = (const float*)d_in[4];
  const float* Whh  = (const float*)d_in[5];
  const float* bih  = (const float*)d_in[6];
  const float* bhh  = (const float*)d_in[7];
  float* out = (float*)d_out;
  unsigned int* flags = (unsigned int*)d_ws;
  unsigned int* hbuf  = (unsigned int*)d_out;

  zero_ws<<<dim3(1056), dim3(512), 0, stream>>>(flags, hbuf);
  lstm_k<<<dim3(256), dim3(512), 0, stream>>>(obs, Wemb, Bemb, Wih, Whh, bih, bhh,
                                              out, flags, hbuf);
}